// Round 3
// baseline (6369.135 us; speedup 1.0000x reference)
//
#include <hip/hip_runtime.h>
#include <cstddef>

// ---------------------------------------------------------------------------
// PointNet++ (B=4, N0=4096, NIN=16, NH=128, NOUT=2, DEPTH=3, K=64, R=2, KNN=3)
// fp32. Selection paths (FPS argmax, radius top-K, 3-NN) use non-contracted
// fp32 ops + first-index tie-breaks to match the reference bit-for-bit.
// FPS uses DPP in-wave argmax (VALU latency, not ds_swizzle) + owner-lane
// register slots so each step has exactly one barrier and no dependent LDS
// chain. SA MLP = compacted batched GEMM over valid (center,point) pairs with
// atomicMax (uint bits, values >= 0) scatter for the max-aggregation.
// ---------------------------------------------------------------------------

#define EPSF 1e-5f

__device__ __forceinline__ float d2_rn(float dx, float dy, float dz) {
    return __fadd_rn(__fadd_rn(__fmul_rn(dx, dx), __fmul_rn(dy, dy)), __fmul_rn(dz, dz));
}

// ---------------- K1: lin_in  xb = relu(x @ W + b), rows=16384 --------------
__global__ __launch_bounds__(128) void lin_in_kernel(
    const float* __restrict__ x, const float* __restrict__ w,
    const float* __restrict__ b, float* __restrict__ xb) {
    __shared__ float sx[16];
    int row = blockIdx.x;
    int t = threadIdx.x;
    if (t < 16) sx[t] = x[row * 16 + t];
    __syncthreads();
    float acc = b[t];
#pragma unroll
    for (int k = 0; k < 16; ++k) acc = fmaf(sx[k], w[k * 128 + t], acc);
    xb[row * 128 + t] = fmaxf(acc, 0.0f);
}

// ---------------- K2: FPS with DPP argmax, 1 barrier/step -------------------
// update_dpp with old=current: invalid/unwritten lanes keep current value, so
// the compare is a no-op there -- exact argmax/first-index semantics.
template <int CTRL, int RMASK>
__device__ __forceinline__ void dpp_amax(float& bv, int& bi) {
    int ov_i = __builtin_amdgcn_update_dpp(__float_as_int(bv), __float_as_int(bv),
                                           CTRL, RMASK, 0xf, false);
    int oi_i = __builtin_amdgcn_update_dpp(bi, bi, CTRL, RMASK, 0xf, false);
    float ov = __int_as_float(ov_i);
    bool take = (ov > bv) || (ov == bv && oi_i < bi);
    bv = take ? ov : bv;
    bi = take ? oi_i : bi;
}

template <int N, int NT>
__global__ __launch_bounds__(NT) void fps_kernel(
    const float* __restrict__ pts, float* __restrict__ q, int m) {
    constexpr int PPT = N / NT;
    constexpr int NW = NT / 64;
    constexpr int LNT = (NT == 1024) ? 10 : (NT == 512) ? 9 : 8;
    __shared__ __align__(16) float s_slot[2][NW][8];  // v, idx, x, y, z, pad
    const int b = blockIdx.x, t = threadIdx.x;
    const int wave = t >> 6;
    const float* P = pts + (size_t)b * N * 3;
    float rx[PPT], ry[PPT], rz[PPT], dmin[PPT];
#pragma unroll
    for (int j = 0; j < PPT; ++j) {
        int i = j * NT + t;
        rx[j] = P[i * 3]; ry[j] = P[i * 3 + 1]; rz[j] = P[i * 3 + 2];
        dmin[j] = 1e30f;
    }
    float lx = P[0], ly = P[1], lz = P[2];
    if (t == 0) { size_t o = (size_t)b * m * 3; q[o] = lx; q[o + 1] = ly; q[o + 2] = lz; }

    for (int step = 1; step < m; ++step) {
        // ---- per-thread dmin update + local argmax (lowest index on ties) ----
        float bv = -1.0f; int bj = 0;
#pragma unroll
        for (int j = 0; j < PPT; ++j) {
            float d = d2_rn(rx[j] - lx, ry[j] - ly, rz[j] - lz);
            float dm = fminf(dmin[j], d);
            dmin[j] = dm;
            if (dm > bv) { bv = dm; bj = j; }   // strict >: first (lowest) index
        }
        int bidx = bj * NT + t;                 // global index; monotone in (j,t)

        // ---- in-wave DPP argmax tree -> lane 63 ----
        dpp_amax<0x111, 0xf>(bv, bidx);  // row_shr:1
        dpp_amax<0x112, 0xf>(bv, bidx);  // row_shr:2
        dpp_amax<0x114, 0xf>(bv, bidx);  // row_shr:4
        dpp_amax<0x118, 0xf>(bv, bidx);  // row_shr:8
        dpp_amax<0x142, 0xa>(bv, bidx);  // row_bcast:15 -> rows 1,3
        dpp_amax<0x143, 0xc>(bv, bidx);  // row_bcast:31 -> rows 2,3

        const float wvv = __int_as_float(__builtin_amdgcn_readlane(__float_as_int(bv), 63));
        const int   wii = __builtin_amdgcn_readlane(bidx, 63);

        const int p = step & 1;
        // owner lane provides winner coords straight from registers
        if (t == (wii & (NT - 1))) {
            const int wj = wii >> LNT;
            float ox = rx[0], oy = ry[0], oz = rz[0];
#pragma unroll
            for (int j = 1; j < PPT; ++j)
                if (j == wj) { ox = rx[j]; oy = ry[j]; oz = rz[j]; }
            float* s = s_slot[p][wave];
            s[0] = wvv; s[1] = __int_as_float(wii);
            s[2] = ox; s[3] = oy; s[4] = oz;
        }
        __syncthreads();

        // ---- cross-wave select (broadcast LDS reads, all independent) ----
        float gv = -2.0f; int gi = 0x7fffffff;
        float nx = 0.f, ny = 0.f, nz = 0.f;
#pragma unroll
        for (int w = 0; w < NW; ++w) {
            const float* s = s_slot[p][w];
            float4 A = *(const float4*)s;       // v, idx, x, y
            float  Z = s[4];
            int si = __float_as_int(A.y);
            bool take = (A.x > gv) || (A.x == gv && si < gi);
            gv = take ? A.x : gv; gi = take ? si : gi;
            nx = take ? A.z : nx; ny = take ? A.w : ny; nz = take ? Z : nz;
        }
        lx = nx; ly = ny; lz = nz;
        if (t == 0) {
            size_t o = (size_t)b * m * 3 + (size_t)step * 3;
            q[o] = lx; q[o + 1] = ly; q[o + 2] = lz;
        }
        // next step writes parity p^1 -> no overwrite hazard; 1 barrier/step
    }
}

// ---------------- K3: zero hout + pair counter ------------------------------
__global__ void zero_kernel(float* __restrict__ buf, int n, unsigned* __restrict__ counter) {
    int i = blockIdx.x * 256 + threadIdx.x;
    if (i < n) buf[i] = 0.0f;
    if (i == 0) *counter = 0u;
}

// ---------------- K4: radius-ball K=64 selection -> compacted pair list -----
template <int CHUNK, int WAVES>
__global__ void nbr_kernel(const float* __restrict__ pts, const float* __restrict__ q,
                           int2* __restrict__ pairs, unsigned* __restrict__ counter,
                           int n, int m) {
    __shared__ float dst[WAVES * CHUNK * 64];
    const int w = threadIdx.x >> 6, lane = threadIdx.x & 63;
    const int c = blockIdx.x * WAVES + w;
    const int b = c / m;
    float* D = dst + w * CHUNK * 64;
    const float* P = pts + (size_t)b * n * 3;
    const float qx = q[(size_t)c * 3 + 0];
    const float qy = q[(size_t)c * 3 + 1];
    const float qz = q[(size_t)c * 3 + 2];
    for (int s = 0; s < CHUNK; ++s) {
        int i = s * 64 + lane;
        float d2 = d2_rn(P[i * 3] - qx, P[i * 3 + 1] - qy, P[i * 3 + 2] - qz);
        D[i] = (d2 <= 4.0f) ? d2 : 1e30f;   // RADIUS^2 = 4
    }
    int my_g = -1;
    int cnt = 0;
    for (int round = 0; round < 64; ++round) {
        float bv = 3e38f;
        int bi = 0x7fffffff;
        for (int s = 0; s < CHUNK; ++s) {
            int i = s * 64 + lane;
            float v = D[i];
            if (v < bv) { bv = v; bi = i; }   // strict <: lowest-index tie-break
        }
#pragma unroll
        for (int off = 32; off >= 1; off >>= 1) {
            float ov = __shfl_xor(bv, off, 64);
            int   oi = __shfl_xor(bi, off, 64);
            if (ov < bv || (ov == bv && oi < bi)) { bv = ov; bi = oi; }
        }
        if (bv > 1e29f) break;               // only invalid/removed remain (uniform)
        if (round == lane) my_g = bi;
        if (lane == (bi & 63)) D[bi] = 3e38f;
        ++cnt;
    }
    unsigned base = 0;
    if (lane == 0) base = atomicAdd(counter, (unsigned)cnt);
    base = (unsigned)__shfl((int)base, 0, 64);
    if (lane < cnt) pairs[base + lane] = make_int2(c, my_g);
}

// ---------------- K5: fused SA MLP over compacted rows ----------------------
__global__ __launch_bounds__(256) void sa_fused_kernel(
    const float* __restrict__ xx, const float* __restrict__ pts,
    const float* __restrict__ q, const int2* __restrict__ pairs,
    const unsigned* __restrict__ vcount,
    const float* __restrict__ w1, const float* __restrict__ b1,
    const float* __restrict__ g1, const float* __restrict__ be1,
    const float* __restrict__ w2, const float* __restrict__ b2,
    const float* __restrict__ g2, const float* __restrict__ be2,
    float* __restrict__ hout, int lm, int ln) {
    __shared__ __align__(16) float shA[64][132];   // gather -> H1 -> out (reused)
    __shared__ __align__(16) float shW[32][132];
    __shared__ int sh_c[64], sh_g[64];
    const int t = threadIdx.x;
    const int V = (int)*vcount;
    const int r0 = blockIdx.x * 64;
    if (r0 >= V) return;
    if (t < 64) {
        int r = r0 + t;
        if (r < V) { int2 p = pairs[r]; sh_c[t] = p.x; sh_g[t] = p.y; }
        else { sh_c[t] = -1; sh_g[t] = 0; }
    }
    __syncthreads();

    // ---- gather A: 64 rows x 132 cols (33 float4 chunks per row) ----
    for (int e = t; e < 64 * 33; e += 256) {
        int row = e / 33, cid = e - row * 33;
        int c = sh_c[row];
        float4 v = make_float4(0.f, 0.f, 0.f, 0.f);
        if (c >= 0) {
            int g = sh_g[row];
            int b = c >> lm;
            size_t pt = ((size_t)(b << ln) + g);
            if (cid < 32) {
                v = *(const float4*)(xx + (pt << 7) + cid * 4);
            } else {
                const float* P = pts + pt * 3;
                const float* Q = q + (size_t)c * 3;
                v.x = P[0] - Q[0]; v.y = P[1] - Q[1]; v.z = P[2] - Q[2]; v.w = 0.f;
            }
        }
        *(float4*)&shA[row][cid * 4] = v;
    }
    __syncthreads();

    const float invs = 1.0f / sqrtf(1.0f + EPSF);
    const int tr = t >> 4, tc = t & 15;       // rows 4tr..4tr+3, cols 8tc..8tc+7
    const int xrow = t >> 2, xcol = t & 3;    // extra cols 128..131
    float acc[32];
#pragma unroll
    for (int i = 0; i < 32; ++i) acc[i] = 0.0f;
    float accx = 0.0f;

    // ---- layer 1: K=132 (rows/cols >=131 zero-padded) ----
    for (int k0 = 0; k0 < 132; k0 += 32) {
        const int kc = (132 - k0 < 32) ? (132 - k0) : 32;
        for (int e = t; e < kc * 132; e += 256) {
            int kk = e / 132, j = e - kk * 132;
            int k = k0 + kk;
            shW[kk][j] = (k < 131 && j < 131) ? w1[k * 131 + j] : 0.0f;
        }
        __syncthreads();
        for (int kk = 0; kk < kc; ++kk) {
            const int k = k0 + kk;
            float a0 = shA[4 * tr + 0][k], a1 = shA[4 * tr + 1][k];
            float a2 = shA[4 * tr + 2][k], a3 = shA[4 * tr + 3][k];
            const float4 w0 = *(const float4*)&shW[kk][8 * tc];
            const float4 w1v = *(const float4*)&shW[kk][8 * tc + 4];
            const float wa[8] = {w0.x, w0.y, w0.z, w0.w, w1v.x, w1v.y, w1v.z, w1v.w};
#pragma unroll
            for (int j = 0; j < 8; ++j) {
                acc[0 * 8 + j] = fmaf(a0, wa[j], acc[0 * 8 + j]);
                acc[1 * 8 + j] = fmaf(a1, wa[j], acc[1 * 8 + j]);
                acc[2 * 8 + j] = fmaf(a2, wa[j], acc[2 * 8 + j]);
                acc[3 * 8 + j] = fmaf(a3, wa[j], acc[3 * 8 + j]);
            }
            accx = fmaf(shA[xrow][k], shW[kk][128 + xcol], accx);
        }
        __syncthreads();
    }
    // epilogue 1 -> H1 into shA
#pragma unroll
    for (int i = 0; i < 4; ++i)
#pragma unroll
        for (int j = 0; j < 8; ++j) {
            int col = 8 * tc + j;
            float z = fmaxf(acc[i * 8 + j] + b1[col], 0.0f);
            shA[4 * tr + i][col] = g1[col] * z * invs + be1[col];
        }
    if (xcol < 3) {
        int col = 128 + xcol;
        float z = fmaxf(accx + b1[col], 0.0f);
        shA[xrow][col] = g1[col] * z * invs + be1[col];
    } else {
        shA[xrow][131] = 0.0f;   // zero K-pad col (w2 row 131 is also zeroed)
    }

    // ---- layer 2: 132 -> 128 ----
#pragma unroll
    for (int i = 0; i < 32; ++i) acc[i] = 0.0f;
    for (int k0 = 0; k0 < 132; k0 += 32) {
        const int kc = (132 - k0 < 32) ? (132 - k0) : 32;
        for (int e = t; e < kc * 132; e += 256) {
            int kk = e / 132, j = e - kk * 132;
            int k = k0 + kk;
            shW[kk][j] = (k < 131 && j < 128) ? w2[k * 128 + j] : 0.0f;
        }
        __syncthreads();
        for (int kk = 0; kk < kc; ++kk) {
            const int k = k0 + kk;
            float a0 = shA[4 * tr + 0][k], a1 = shA[4 * tr + 1][k];
            float a2 = shA[4 * tr + 2][k], a3 = shA[4 * tr + 3][k];
            const float4 w0 = *(const float4*)&shW[kk][8 * tc];
            const float4 w1v = *(const float4*)&shW[kk][8 * tc + 4];
            const float wa[8] = {w0.x, w0.y, w0.z, w0.w, w1v.x, w1v.y, w1v.z, w1v.w};
#pragma unroll
            for (int j = 0; j < 8; ++j) {
                acc[0 * 8 + j] = fmaf(a0, wa[j], acc[0 * 8 + j]);
                acc[1 * 8 + j] = fmaf(a1, wa[j], acc[1 * 8 + j]);
                acc[2 * 8 + j] = fmaf(a2, wa[j], acc[2 * 8 + j]);
                acc[3 * 8 + j] = fmaf(a3, wa[j], acc[3 * 8 + j]);
            }
        }
        __syncthreads();
    }
    // epilogue 2 -> out into shA (cols 0..127)
#pragma unroll
    for (int i = 0; i < 4; ++i)
#pragma unroll
        for (int j = 0; j < 8; ++j) {
            int col = 8 * tc + j;
            float z = fmaxf(acc[i * 8 + j] + b2[col], 0.0f);
            shA[4 * tr + i][col] = g2[col] * z * invs + be2[col];
        }
    __syncthreads();

    // ---- segmented max over contiguous same-center rows + atomic scatter ----
    if (t < 128) {
        const int col = t;
        float run = -1.0f;
        int cur = sh_c[0];
        for (int row = 0; row < 64; ++row) {
            int c = sh_c[row];
            if (c != cur) {
                if (cur >= 0)
                    atomicMax((unsigned*)&hout[((size_t)cur << 7) + col], __float_as_uint(run));
                run = -1.0f; cur = c;
            }
            run = fmaxf(run, shA[row][col]);
        }
        if (cur >= 0)
            atomicMax((unsigned*)&hout[((size_t)cur << 7) + col], __float_as_uint(run));
    }
}

// ---------------- K6a: 3-NN search + inverse-d2 weights --------------------
__global__ __launch_bounds__(256) void knn_kernel(
    const float* __restrict__ pf, const float* __restrict__ pc,
    int* __restrict__ kidx, float* __restrict__ kw, int nf, int nc) {
    const int tg = blockIdx.x * 256 + threadIdx.x;
    const int b = tg / nf;
    const float* F = pf + (size_t)tg * 3;
    const float fx = F[0], fy = F[1], fz = F[2];
    const float* C = pc + (size_t)b * nc * 3;
    float b0 = 1e30f, b1 = 1e30f, b2 = 1e30f;
    int i0 = 0, i1 = 0, i2 = 0;
    for (int j = 0; j < nc; ++j) {
        float d2 = d2_rn(C[j * 3] - fx, C[j * 3 + 1] - fy, C[j * 3 + 2] - fz);
        if (d2 < b0)      { b2 = b1; i2 = i1; b1 = b0; i1 = i0; b0 = d2; i0 = j; }
        else if (d2 < b1) { b2 = b1; i2 = i1; b1 = d2; i1 = j; }
        else if (d2 < b2) { b2 = d2; i2 = j; }
    }
    float w0 = 1.0f / fmaxf(b0, 1e-16f);
    float w1 = 1.0f / fmaxf(b1, 1e-16f);
    float w2 = 1.0f / fmaxf(b2, 1e-16f);
    float inv = 1.0f / (w0 + w1 + w2);
    size_t o = (size_t)tg * 3;
    kidx[o] = i0; kidx[o + 1] = i1; kidx[o + 2] = i2;
    kw[o] = w0 * inv; kw[o + 1] = w1 * inv; kw[o + 2] = w2 * inv;
}

// ---------------- K6b: interpolate + concat skip -> cat[f][256] -------------
__global__ __launch_bounds__(256) void interp_cat_kernel(
    const float* __restrict__ xc, const float* __restrict__ xs,
    const int* __restrict__ kidx, const float* __restrict__ kw,
    float* __restrict__ cat, int nf, int nc) {
    const int f = blockIdx.x;
    const int t = threadIdx.x;
    const int b = f / nf;
    const size_t o = (size_t)f * 3;
    if (t < 128) {
        int i0 = kidx[o], i1 = kidx[o + 1], i2 = kidx[o + 2];
        float w0 = kw[o], w1 = kw[o + 1], w2 = kw[o + 2];
        const float* X = xc + (size_t)b * nc * 128;
        float y = w0 * X[(size_t)i0 * 128 + t] + w1 * X[(size_t)i1 * 128 + t] +
                  w2 * X[(size_t)i2 * 128 + t];
        cat[(size_t)f * 256 + t] = y;
    } else {
        cat[(size_t)f * 256 + t] = xs[(size_t)f * 128 + (t - 128)];
    }
}

// ---------------- K7: generic GEMM + bias + relu + BN epilogue --------------
__global__ __launch_bounds__(256) void gemm_bn_kernel(
    const float* __restrict__ A, const float* __restrict__ W,
    const float* __restrict__ bias, const float* __restrict__ g,
    const float* __restrict__ be, float* __restrict__ C, int Kin, int Cout) {
    __shared__ __align__(16) float shA[64][33];
    __shared__ __align__(16) float shB[32][68];
    const int t = threadIdx.x;
    const int r0 = blockIdx.x * 64;
    const int c0 = blockIdx.y * 64;
    const int tr = t >> 4, tc = t & 15;
    const float invs = 1.0f / sqrtf(1.0f + EPSF);
    float acc[16];
#pragma unroll
    for (int i = 0; i < 16; ++i) acc[i] = 0.0f;
    for (int k0 = 0; k0 < Kin; k0 += 32) {
#pragma unroll
        for (int e = t; e < 2048; e += 256) {
            int r = e >> 5, kk = e & 31;
            shA[r][kk] = A[(size_t)(r0 + r) * Kin + k0 + kk];
        }
#pragma unroll
        for (int e = t; e < 2048; e += 256) {
            int kk = e >> 6, cc = e & 63;
            shB[kk][cc] = W[(size_t)(k0 + kk) * Cout + c0 + cc];
        }
        __syncthreads();
        for (int kk = 0; kk < 32; ++kk) {
            float av[4];
#pragma unroll
            for (int i = 0; i < 4; ++i) av[i] = shA[4 * tr + i][kk];
            const float4 wv = *(const float4*)&shB[kk][4 * tc];
            const float wa[4] = {wv.x, wv.y, wv.z, wv.w};
#pragma unroll
            for (int i = 0; i < 4; ++i)
#pragma unroll
                for (int jj = 0; jj < 4; ++jj)
                    acc[i * 4 + jj] = fmaf(av[i], wa[jj], acc[i * 4 + jj]);
        }
        __syncthreads();
    }
#pragma unroll
    for (int i = 0; i < 4; ++i)
#pragma unroll
        for (int jj = 0; jj < 4; ++jj) {
            int col = c0 + 4 * tc + jj;
            float z = fmaxf(acc[i * 4 + jj] + bias[col], 0.0f);
            C[(size_t)(r0 + 4 * tr + i) * Cout + col] = g[col] * z * invs + be[col];
        }
}

// ---------------- K8: final 128 -> 2 layer ----------------------------------
__global__ __launch_bounds__(256) void lo2_kernel(
    const float* __restrict__ in, const float* __restrict__ w,
    const float* __restrict__ b, const float* __restrict__ g,
    const float* __restrict__ be, float* __restrict__ out) {
    __shared__ float sw[256];
    const int t = threadIdx.x;
    sw[t] = w[t];
    __syncthreads();
    const int row = blockIdx.x * 256 + t;
    const float invs = 1.0f / sqrtf(1.0f + EPSF);
    float a0 = b[0], a1 = b[1];
    const float* R = in + (size_t)row * 128;
    for (int k = 0; k < 128; ++k) {
        float a = R[k];
        a0 = fmaf(a, sw[k * 2], a0);
        a1 = fmaf(a, sw[k * 2 + 1], a1);
    }
    a0 = fmaxf(a0, 0.0f);
    a1 = fmaxf(a1, 0.0f);
    out[(size_t)row * 2]     = g[0] * a0 * invs + be[0];
    out[(size_t)row * 2 + 1] = g[1] * a1 * invs + be[1];
}

// ---------------------------------------------------------------------------
extern "C" void kernel_launch(void* const* d_in, const int* in_sizes, int n_in,
                              void* d_out, int out_size, void* d_ws, size_t ws_size,
                              hipStream_t stream) {
    const float* x      = (const float*)d_in[0];
    const float* pos    = (const float*)d_in[1];
    const float* lin_w  = (const float*)d_in[3];
    const float* lin_b  = (const float*)d_in[4];
    const float* sa_w1  = (const float*)d_in[5];
    const float* sa_b1  = (const float*)d_in[6];
    const float* sa_g1  = (const float*)d_in[7];
    const float* sa_be1 = (const float*)d_in[8];
    const float* sa_w2  = (const float*)d_in[9];
    const float* sa_b2  = (const float*)d_in[10];
    const float* sa_g2  = (const float*)d_in[11];
    const float* sa_be2 = (const float*)d_in[12];
    const float* fp_w1  = (const float*)d_in[13];
    const float* fp_b1  = (const float*)d_in[14];
    const float* fp_g1  = (const float*)d_in[15];
    const float* fp_be1 = (const float*)d_in[16];
    const float* fp_w2  = (const float*)d_in[17];
    const float* fp_b2  = (const float*)d_in[18];
    const float* fp_g2  = (const float*)d_in[19];
    const float* fp_be2 = (const float*)d_in[20];
    const float* lo_w1  = (const float*)d_in[21];
    const float* lo_b1  = (const float*)d_in[22];
    const float* lo_g1  = (const float*)d_in[23];
    const float* lo_be1 = (const float*)d_in[24];
    const float* lo_w2  = (const float*)d_in[25];
    const float* lo_b2  = (const float*)d_in[26];
    const float* lo_g2  = (const float*)d_in[27];
    const float* lo_be2 = (const float*)d_in[28];

    float* ws = (float*)d_ws;
    size_t off = 0;
    auto alloc = [&](size_t n) { float* p = ws + off; off += n; return p; };
    float* xb    = alloc(4 * 4096 * 128);
    float* q1    = alloc(4 * 2048 * 3);
    float* q2    = alloc(4 * 1024 * 3);
    float* q3    = alloc(4 * 512 * 3);
    float* h1    = alloc(4 * 2048 * 128);
    float* h2    = alloc(4 * 1024 * 128);
    float* h3    = alloc(4 * 512 * 128);
    int2* pairs1 = (int2*)alloc(4 * 2048 * 64 * 2);
    int2* pairs2 = (int2*)alloc(4 * 1024 * 64 * 2);
    int2* pairs3 = (int2*)alloc(4 * 512 * 64 * 2);
    unsigned* ctrs = (unsigned*)alloc(64);   // [0],[16],[32] per level
    int* kidx    = (int*)alloc(4 * 4096 * 3);
    float* kw    = alloc(4 * 4096 * 3);
    float* cat   = alloc(4 * 4096 * 256);
    float* mbuf  = alloc(4 * 4096 * 256);
    float* xfA   = alloc(4 * 4096 * 128);
    float* xfB   = alloc(4 * 4096 * 128);
    if (ws_size < off * sizeof(float)) return;

    lin_in_kernel<<<16384, 128, 0, stream>>>(x, lin_w, lin_b, xb);

    // ---- SA level 0: 4096 -> 2048 ----
    fps_kernel<4096, 512><<<4, 512, 0, stream>>>(pos, q1, 2048);
    zero_kernel<<<(4 * 2048 * 128 + 255) / 256, 256, 0, stream>>>(h1, 4 * 2048 * 128, ctrs + 0);
    nbr_kernel<64, 2><<<4096, 128, 0, stream>>>(pos, q1, pairs1, ctrs + 0, 4096, 2048);
    sa_fused_kernel<<<8192, 256, 0, stream>>>(xb, pos, q1, pairs1, ctrs + 0,
        sa_w1, sa_b1, sa_g1, sa_be1, sa_w2, sa_b2, sa_g2, sa_be2, h1, 11, 12);

    // ---- SA level 1: 2048 -> 1024 ----
    fps_kernel<2048, 256><<<4, 256, 0, stream>>>(q1, q2, 1024);
    zero_kernel<<<(4 * 1024 * 128 + 255) / 256, 256, 0, stream>>>(h2, 4 * 1024 * 128, ctrs + 16);
    nbr_kernel<32, 4><<<1024, 256, 0, stream>>>(q1, q2, pairs2, ctrs + 16, 2048, 1024);
    sa_fused_kernel<<<4096, 256, 0, stream>>>(h1, q1, q2, pairs2, ctrs + 16,
        sa_w1 + 131 * 131, sa_b1 + 131, sa_g1 + 131, sa_be1 + 131,
        sa_w2 + 131 * 128, sa_b2 + 128, sa_g2 + 128, sa_be2 + 128, h2, 10, 11);

    // ---- SA level 2: 1024 -> 512 ----
    fps_kernel<1024, 256><<<4, 256, 0, stream>>>(q2, q3, 512);
    zero_kernel<<<(4 * 512 * 128 + 255) / 256, 256, 0, stream>>>(h3, 4 * 512 * 128, ctrs + 32);
    nbr_kernel<16, 4><<<512, 256, 0, stream>>>(q2, q3, pairs3, ctrs + 32, 1024, 512);
    sa_fused_kernel<<<2048, 256, 0, stream>>>(h2, q2, q3, pairs3, ctrs + 32,
        sa_w1 + 2 * 131 * 131, sa_b1 + 2 * 131, sa_g1 + 2 * 131, sa_be1 + 2 * 131,
        sa_w2 + 2 * 131 * 128, sa_b2 + 2 * 128, sa_g2 + 2 * 128, sa_be2 + 2 * 128, h3, 9, 10);

    // ---- FP step 0 (mi=2): 512 -> 1024 ----
    knn_kernel<<<(4 * 1024) / 256, 256, 0, stream>>>(q2, q3, kidx, kw, 1024, 512);
    interp_cat_kernel<<<4 * 1024, 256, 0, stream>>>(h3, h2, kidx, kw, cat, 1024, 512);
    gemm_bn_kernel<<<dim3(4096 / 64, 4), 256, 0, stream>>>(cat,
        fp_w1 + 2 * 256 * 256, fp_b1 + 2 * 256, fp_g1 + 2 * 256, fp_be1 + 2 * 256,
        mbuf, 256, 256);
    gemm_bn_kernel<<<dim3(4096 / 64, 2), 256, 0, stream>>>(mbuf,
        fp_w2 + 2 * 256 * 128, fp_b2 + 2 * 128, fp_g2 + 2 * 128, fp_be2 + 2 * 128,
        xfA, 256, 128);

    // ---- FP step 1 (mi=1): 1024 -> 2048 ----
    knn_kernel<<<(4 * 2048) / 256, 256, 0, stream>>>(q1, q2, kidx, kw, 2048, 1024);
    interp_cat_kernel<<<4 * 2048, 256, 0, stream>>>(xfA, h1, kidx, kw, cat, 2048, 1024);
    gemm_bn_kernel<<<dim3(8192 / 64, 4), 256, 0, stream>>>(cat,
        fp_w1 + 256 * 256, fp_b1 + 256, fp_g1 + 256, fp_be1 + 256,
        mbuf, 256, 256);
    gemm_bn_kernel<<<dim3(8192 / 64, 2), 256, 0, stream>>>(mbuf,
        fp_w2 + 256 * 128, fp_b2 + 128, fp_g2 + 128, fp_be2 + 128,
        xfB, 256, 128);

    // ---- FP step 2 (mi=0): 2048 -> 4096 ----
    knn_kernel<<<(4 * 4096) / 256, 256, 0, stream>>>(pos, q1, kidx, kw, 4096, 2048);
    interp_cat_kernel<<<4 * 4096, 256, 0, stream>>>(xfB, xb, kidx, kw, cat, 4096, 2048);
    gemm_bn_kernel<<<dim3(16384 / 64, 4), 256, 0, stream>>>(cat,
        fp_w1, fp_b1, fp_g1, fp_be1, mbuf, 256, 256);
    gemm_bn_kernel<<<dim3(16384 / 64, 2), 256, 0, stream>>>(mbuf,
        fp_w2, fp_b2, fp_g2, fp_be2, xfA, 256, 128);

    // ---- output MLP ----
    gemm_bn_kernel<<<dim3(16384 / 64, 2), 256, 0, stream>>>(xfA,
        lo_w1, lo_b1, lo_g1, lo_be1, mbuf, 128, 128);
    lo2_kernel<<<16384 / 256, 256, 0, stream>>>(mbuf, lo_w2, lo_b2, lo_g2, lo_be2,
        (float*)d_out);
}

// Round 4
// 4724.105 us; speedup vs baseline: 1.3482x; 1.3482x over previous
//
#include <hip/hip_runtime.h>
#include <cstddef>

// ---------------------------------------------------------------------------
// PointNet++ (B=4, N0=4096, NIN=16, NH=128, NOUT=2, DEPTH=3, K=64, R=2, KNN=3)
// fp32. Selection paths (FPS argmax, radius top-K, 3-NN) use non-contracted
// fp32 ops + first-index tie-breaks to match the reference bit-for-bit.
// FPS: f64-sortable-key argmax (hi=dist bits, lo=~index -> positive-double
// compare == (value, first-index) order), DPP in-wave tree, lane-parallel
// cross-wave reduce (2 ds_reads/wave/step), q buffered in LDS (no global
// stores in the serial loop). SA MLP = compacted batched GEMM over valid
// (center,point) pairs with atomicMax (uint bits, values >= 0) scatter.
// ---------------------------------------------------------------------------

#define EPSF 1e-5f

__device__ __forceinline__ float d2_rn(float dx, float dy, float dz) {
    return __fadd_rn(__fadd_rn(__fmul_rn(dx, dx), __fmul_rn(dy, dy)), __fmul_rn(dz, dz));
}

__device__ __forceinline__ float readlane_f(float v, int l) {
    return __int_as_float(__builtin_amdgcn_readlane(__float_as_int(v), l));
}

// ---------------- K1: lin_in  xb = relu(x @ W + b), rows=16384 --------------
__global__ __launch_bounds__(128) void lin_in_kernel(
    const float* __restrict__ x, const float* __restrict__ w,
    const float* __restrict__ b, float* __restrict__ xb) {
    __shared__ float sx[16];
    int row = blockIdx.x;
    int t = threadIdx.x;
    if (t < 16) sx[t] = x[row * 16 + t];
    __syncthreads();
    float acc = b[t];
#pragma unroll
    for (int k = 0; k < 16; ++k) acc = fmaf(sx[k], w[k * 128 + t], acc);
    xb[row * 128 + t] = fmaxf(acc, 0.0f);
}

// ---------------- K2: FPS with f64-key DPP argmax ---------------------------
// key = hiloint2double(float_bits(dmin), ~index): both words make a positive
// finite double (dmin in [0,768]); positive doubles order like their uint64
// bits, so max(key) == (max dmin, then lowest index). Exact ref semantics.
template <int CTRL, int RMASK>
__device__ __forceinline__ double dpp_mov64(double k) {
    int lo = __builtin_amdgcn_update_dpp(__double2loint(k), __double2loint(k),
                                         CTRL, RMASK, 0xf, false);
    int hi = __builtin_amdgcn_update_dpp(__double2hiint(k), __double2hiint(k),
                                         CTRL, RMASK, 0xf, false);
    return __hiloint2double(hi, lo);
}

template <int N, int NT>
__global__ __launch_bounds__(NT) void fps_kernel(
    const float* __restrict__ pts, float* __restrict__ q, int m) {
    constexpr int PPT = N / NT;
    constexpr int NW = NT / 64;
    constexpr int LNT = (NT == 512) ? 9 : 8;
    __shared__ __align__(16) float s_q[N / 2][4];       // selected coords buffer
    __shared__ __align__(16) float s_slot[2][NW][8];    // klo,khi,x,y,z
    const int b = blockIdx.x, t = threadIdx.x;
    const int wave = t >> 6, lane = t & 63;
    const float* P = pts + (size_t)b * N * 3;
    float rx[PPT], ry[PPT], rz[PPT], dmin[PPT];
#pragma unroll
    for (int j = 0; j < PPT; ++j) {
        int i = (j << LNT) + t;
        rx[j] = P[i * 3]; ry[j] = P[i * 3 + 1]; rz[j] = P[i * 3 + 2];
        dmin[j] = 1e30f;
    }
    float lx = P[0], ly = P[1], lz = P[2];
    if (t == 0) { s_q[0][0] = lx; s_q[0][1] = ly; s_q[0][2] = lz; }

    for (int step = 1; step < m; ++step) {
        // ---- dmin update + local argmax (first index on ties) ----
        float bv = -1.0f; int klo = 0;
#pragma unroll
        for (int j = 0; j < PPT; ++j) {
            float d = d2_rn(rx[j] - lx, ry[j] - ly, rz[j] - lz);
            float dm = fminf(dmin[j], d);
            dmin[j] = dm;
            int kloj = ~((j << LNT) + t);
            if (dm > bv) { bv = dm; klo = kloj; }   // strict >: lowest j wins
        }
        double key = __hiloint2double(__float_as_int(bv), klo);

        // ---- in-wave DPP max tree -> lane 63 ----
        key = fmax(key, dpp_mov64<0x111, 0xf>(key));  // row_shr:1
        key = fmax(key, dpp_mov64<0x112, 0xf>(key));  // row_shr:2
        key = fmax(key, dpp_mov64<0x114, 0xf>(key));  // row_shr:4
        key = fmax(key, dpp_mov64<0x118, 0xf>(key));  // row_shr:8
        key = fmax(key, dpp_mov64<0x142, 0xa>(key));  // row_bcast:15
        key = fmax(key, dpp_mov64<0x143, 0xc>(key));  // row_bcast:31

        const int wk_lo = __builtin_amdgcn_readlane(__double2loint(key), 63);
        const int wi = ~wk_lo;                         // this wave's winner index
        const int p = step & 1;
        if (t == (wi & (NT - 1))) {                    // owner thread (this wave)
            const int wj = wi >> LNT;
            float ox = rx[0], oy = ry[0], oz = rz[0];
#pragma unroll
            for (int j = 1; j < PPT; ++j)
                if (j == wj) { ox = rx[j]; oy = ry[j]; oz = rz[j]; }
            float* s = s_slot[p][wave];
            const int wk_hi = __builtin_amdgcn_readlane(__double2hiint(key), 63);
            *(float4*)s = make_float4(__int_as_float(wk_lo), __int_as_float(wk_hi), ox, oy);
            s[4] = oz;
        }
        __syncthreads();

        // ---- cross-wave: lane-parallel slot read + small DPP tree ----
        const float* sl = s_slot[p][lane & (NW - 1)];
        float4 A = *(const float4*)sl;     // klo, khi, x, y
        float  Z = sl[4];                  // z
        double ck = __hiloint2double(__float_as_int(A.y), __float_as_int(A.x));
        double mk = ck;
        mk = fmax(mk, dpp_mov64<0x111, 0xf>(mk));
        mk = fmax(mk, dpp_mov64<0x112, 0xf>(mk));
        if (NW == 8) mk = fmax(mk, dpp_mov64<0x114, 0xf>(mk));
        const int g_lo = __builtin_amdgcn_readlane(__double2loint(mk), NW - 1);
        const int g_hi = __builtin_amdgcn_readlane(__double2hiint(mk), NW - 1);
        bool match = (lane < NW) && (__float_as_int(A.x) == g_lo) &&
                     (__float_as_int(A.y) == g_hi);
        unsigned long long mb = __ballot(match);
        const int sWin = __ffsll((long long)mb) - 1;   // uniform
        lx = readlane_f(A.z, sWin);
        ly = readlane_f(A.w, sWin);
        lz = readlane_f(Z, sWin);
        if (t == 0) *(float4*)s_q[step] = make_float4(lx, ly, lz, 0.0f);
        // next step writes parity p^1 -> no overwrite hazard; 1 barrier/step
    }
    __syncthreads();
    // ---- coalesced-ish flush of selected coords ----
    for (int e = t; e < m; e += NT) {
        float4 v = *(const float4*)s_q[e];
        size_t o = ((size_t)b * m + e) * 3;
        q[o] = v.x; q[o + 1] = v.y; q[o + 2] = v.z;
    }
}

// ---------------- K3: zero hout + pair counter ------------------------------
__global__ void zero_kernel(float* __restrict__ buf, int n, unsigned* __restrict__ counter) {
    int i = blockIdx.x * 256 + threadIdx.x;
    if (i < n) buf[i] = 0.0f;
    if (i == 0) *counter = 0u;
}

// ---------------- K4: radius-ball K=64 selection -> compacted pair list -----
template <int CHUNK, int WAVES>
__global__ void nbr_kernel(const float* __restrict__ pts, const float* __restrict__ q,
                           int2* __restrict__ pairs, unsigned* __restrict__ counter,
                           int n, int m) {
    __shared__ float dst[WAVES * CHUNK * 64];
    const int w = threadIdx.x >> 6, lane = threadIdx.x & 63;
    const int c = blockIdx.x * WAVES + w;
    const int b = c / m;
    float* D = dst + w * CHUNK * 64;
    const float* P = pts + (size_t)b * n * 3;
    const float qx = q[(size_t)c * 3 + 0];
    const float qy = q[(size_t)c * 3 + 1];
    const float qz = q[(size_t)c * 3 + 2];
    for (int s = 0; s < CHUNK; ++s) {
        int i = s * 64 + lane;
        float d2 = d2_rn(P[i * 3] - qx, P[i * 3 + 1] - qy, P[i * 3 + 2] - qz);
        D[i] = (d2 <= 4.0f) ? d2 : 1e30f;   // RADIUS^2 = 4
    }
    int my_g = -1;
    int cnt = 0;
    for (int round = 0; round < 64; ++round) {
        float bv = 3e38f;
        int bi = 0x7fffffff;
        for (int s = 0; s < CHUNK; ++s) {
            int i = s * 64 + lane;
            float v = D[i];
            if (v < bv) { bv = v; bi = i; }   // strict <: lowest-index tie-break
        }
#pragma unroll
        for (int off = 32; off >= 1; off >>= 1) {
            float ov = __shfl_xor(bv, off, 64);
            int   oi = __shfl_xor(bi, off, 64);
            if (ov < bv || (ov == bv && oi < bi)) { bv = ov; bi = oi; }
        }
        if (bv > 1e29f) break;               // only invalid/removed remain (uniform)
        if (round == lane) my_g = bi;
        if (lane == (bi & 63)) D[bi] = 3e38f;
        ++cnt;
    }
    unsigned base = 0;
    if (lane == 0) base = atomicAdd(counter, (unsigned)cnt);
    base = (unsigned)__shfl((int)base, 0, 64);
    if (lane < cnt) pairs[base + lane] = make_int2(c, my_g);
}

// ---------------- K5: fused SA MLP over compacted rows ----------------------
__global__ __launch_bounds__(256) void sa_fused_kernel(
    const float* __restrict__ xx, const float* __restrict__ pts,
    const float* __restrict__ q, const int2* __restrict__ pairs,
    const unsigned* __restrict__ vcount,
    const float* __restrict__ w1, const float* __restrict__ b1,
    const float* __restrict__ g1, const float* __restrict__ be1,
    const float* __restrict__ w2, const float* __restrict__ b2,
    const float* __restrict__ g2, const float* __restrict__ be2,
    float* __restrict__ hout, int lm, int ln) {
    __shared__ __align__(16) float shA[64][132];   // gather -> H1 -> out (reused)
    __shared__ __align__(16) float shW[32][132];
    __shared__ int sh_c[64], sh_g[64];
    const int t = threadIdx.x;
    const int V = (int)*vcount;
    const int r0 = blockIdx.x * 64;
    if (r0 >= V) return;
    if (t < 64) {
        int r = r0 + t;
        if (r < V) { int2 p = pairs[r]; sh_c[t] = p.x; sh_g[t] = p.y; }
        else { sh_c[t] = -1; sh_g[t] = 0; }
    }
    __syncthreads();

    // ---- gather A: 64 rows x 132 cols (33 float4 chunks per row) ----
    for (int e = t; e < 64 * 33; e += 256) {
        int row = e / 33, cid = e - row * 33;
        int c = sh_c[row];
        float4 v = make_float4(0.f, 0.f, 0.f, 0.f);
        if (c >= 0) {
            int g = sh_g[row];
            int b = c >> lm;
            size_t pt = ((size_t)(b << ln) + g);
            if (cid < 32) {
                v = *(const float4*)(xx + (pt << 7) + cid * 4);
            } else {
                const float* P = pts + pt * 3;
                const float* Q = q + (size_t)c * 3;
                v.x = P[0] - Q[0]; v.y = P[1] - Q[1]; v.z = P[2] - Q[2]; v.w = 0.f;
            }
        }
        *(float4*)&shA[row][cid * 4] = v;
    }
    __syncthreads();

    const float invs = 1.0f / sqrtf(1.0f + EPSF);
    const int tr = t >> 4, tc = t & 15;       // rows 4tr..4tr+3, cols 8tc..8tc+7
    const int xrow = t >> 2, xcol = t & 3;    // extra cols 128..131
    float acc[32];
#pragma unroll
    for (int i = 0; i < 32; ++i) acc[i] = 0.0f;
    float accx = 0.0f;

    // ---- layer 1: K=132 (rows/cols >=131 zero-padded) ----
    for (int k0 = 0; k0 < 132; k0 += 32) {
        const int kc = (132 - k0 < 32) ? (132 - k0) : 32;
        for (int e = t; e < kc * 132; e += 256) {
            int kk = e / 132, j = e - kk * 132;
            int k = k0 + kk;
            shW[kk][j] = (k < 131 && j < 131) ? w1[k * 131 + j] : 0.0f;
        }
        __syncthreads();
        for (int kk = 0; kk < kc; ++kk) {
            const int k = k0 + kk;
            float a0 = shA[4 * tr + 0][k], a1 = shA[4 * tr + 1][k];
            float a2 = shA[4 * tr + 2][k], a3 = shA[4 * tr + 3][k];
            const float4 w0 = *(const float4*)&shW[kk][8 * tc];
            const float4 w1v = *(const float4*)&shW[kk][8 * tc + 4];
            const float wa[8] = {w0.x, w0.y, w0.z, w0.w, w1v.x, w1v.y, w1v.z, w1v.w};
#pragma unroll
            for (int j = 0; j < 8; ++j) {
                acc[0 * 8 + j] = fmaf(a0, wa[j], acc[0 * 8 + j]);
                acc[1 * 8 + j] = fmaf(a1, wa[j], acc[1 * 8 + j]);
                acc[2 * 8 + j] = fmaf(a2, wa[j], acc[2 * 8 + j]);
                acc[3 * 8 + j] = fmaf(a3, wa[j], acc[3 * 8 + j]);
            }
            accx = fmaf(shA[xrow][k], shW[kk][128 + xcol], accx);
        }
        __syncthreads();
    }
    // epilogue 1 -> H1 into shA
#pragma unroll
    for (int i = 0; i < 4; ++i)
#pragma unroll
        for (int j = 0; j < 8; ++j) {
            int col = 8 * tc + j;
            float z = fmaxf(acc[i * 8 + j] + b1[col], 0.0f);
            shA[4 * tr + i][col] = g1[col] * z * invs + be1[col];
        }
    if (xcol < 3) {
        int col = 128 + xcol;
        float z = fmaxf(accx + b1[col], 0.0f);
        shA[xrow][col] = g1[col] * z * invs + be1[col];
    } else {
        shA[xrow][131] = 0.0f;   // zero K-pad col (w2 row 131 is also zeroed)
    }

    // ---- layer 2: 132 -> 128 ----
#pragma unroll
    for (int i = 0; i < 32; ++i) acc[i] = 0.0f;
    for (int k0 = 0; k0 < 132; k0 += 32) {
        const int kc = (132 - k0 < 32) ? (132 - k0) : 32;
        for (int e = t; e < kc * 132; e += 256) {
            int kk = e / 132, j = e - kk * 132;
            int k = k0 + kk;
            shW[kk][j] = (k < 131 && j < 128) ? w2[k * 128 + j] : 0.0f;
        }
        __syncthreads();
        for (int kk = 0; kk < kc; ++kk) {
            const int k = k0 + kk;
            float a0 = shA[4 * tr + 0][k], a1 = shA[4 * tr + 1][k];
            float a2 = shA[4 * tr + 2][k], a3 = shA[4 * tr + 3][k];
            const float4 w0 = *(const float4*)&shW[kk][8 * tc];
            const float4 w1v = *(const float4*)&shW[kk][8 * tc + 4];
            const float wa[8] = {w0.x, w0.y, w0.z, w0.w, w1v.x, w1v.y, w1v.z, w1v.w};
#pragma unroll
            for (int j = 0; j < 8; ++j) {
                acc[0 * 8 + j] = fmaf(a0, wa[j], acc[0 * 8 + j]);
                acc[1 * 8 + j] = fmaf(a1, wa[j], acc[1 * 8 + j]);
                acc[2 * 8 + j] = fmaf(a2, wa[j], acc[2 * 8 + j]);
                acc[3 * 8 + j] = fmaf(a3, wa[j], acc[3 * 8 + j]);
            }
        }
        __syncthreads();
    }
    // epilogue 2 -> out into shA (cols 0..127)
#pragma unroll
    for (int i = 0; i < 4; ++i)
#pragma unroll
        for (int j = 0; j < 8; ++j) {
            int col = 8 * tc + j;
            float z = fmaxf(acc[i * 8 + j] + b2[col], 0.0f);
            shA[4 * tr + i][col] = g2[col] * z * invs + be2[col];
        }
    __syncthreads();

    // ---- segmented max over contiguous same-center rows + atomic scatter ----
    if (t < 128) {
        const int col = t;
        float run = -1.0f;
        int cur = sh_c[0];
        for (int row = 0; row < 64; ++row) {
            int c = sh_c[row];
            if (c != cur) {
                if (cur >= 0)
                    atomicMax((unsigned*)&hout[((size_t)cur << 7) + col], __float_as_uint(run));
                run = -1.0f; cur = c;
            }
            run = fmaxf(run, shA[row][col]);
        }
        if (cur >= 0)
            atomicMax((unsigned*)&hout[((size_t)cur << 7) + col], __float_as_uint(run));
    }
}

// ---------------- K6a: 3-NN search + inverse-d2 weights --------------------
__global__ __launch_bounds__(256) void knn_kernel(
    const float* __restrict__ pf, const float* __restrict__ pc,
    int* __restrict__ kidx, float* __restrict__ kw, int nf, int nc) {
    const int tg = blockIdx.x * 256 + threadIdx.x;
    const int b = tg / nf;
    const float* F = pf + (size_t)tg * 3;
    const float fx = F[0], fy = F[1], fz = F[2];
    const float* C = pc + (size_t)b * nc * 3;
    float b0 = 1e30f, b1 = 1e30f, b2 = 1e30f;
    int i0 = 0, i1 = 0, i2 = 0;
    for (int j = 0; j < nc; ++j) {
        float d2 = d2_rn(C[j * 3] - fx, C[j * 3 + 1] - fy, C[j * 3 + 2] - fz);
        if (d2 < b0)      { b2 = b1; i2 = i1; b1 = b0; i1 = i0; b0 = d2; i0 = j; }
        else if (d2 < b1) { b2 = b1; i2 = i1; b1 = d2; i1 = j; }
        else if (d2 < b2) { b2 = d2; i2 = j; }
    }
    float w0 = 1.0f / fmaxf(b0, 1e-16f);
    float w1 = 1.0f / fmaxf(b1, 1e-16f);
    float w2 = 1.0f / fmaxf(b2, 1e-16f);
    float inv = 1.0f / (w0 + w1 + w2);
    size_t o = (size_t)tg * 3;
    kidx[o] = i0; kidx[o + 1] = i1; kidx[o + 2] = i2;
    kw[o] = w0 * inv; kw[o + 1] = w1 * inv; kw[o + 2] = w2 * inv;
}

// ---------------- K6b: interpolate + concat skip -> cat[f][256] -------------
__global__ __launch_bounds__(256) void interp_cat_kernel(
    const float* __restrict__ xc, const float* __restrict__ xs,
    const int* __restrict__ kidx, const float* __restrict__ kw,
    float* __restrict__ cat, int nf, int nc) {
    const int f = blockIdx.x;
    const int t = threadIdx.x;
    const int b = f / nf;
    const size_t o = (size_t)f * 3;
    if (t < 128) {
        int i0 = kidx[o], i1 = kidx[o + 1], i2 = kidx[o + 2];
        float w0 = kw[o], w1 = kw[o + 1], w2 = kw[o + 2];
        const float* X = xc + (size_t)b * nc * 128;
        float y = w0 * X[(size_t)i0 * 128 + t] + w1 * X[(size_t)i1 * 128 + t] +
                  w2 * X[(size_t)i2 * 128 + t];
        cat[(size_t)f * 256 + t] = y;
    } else {
        cat[(size_t)f * 256 + t] = xs[(size_t)f * 128 + (t - 128)];
    }
}

// ---------------- K7: generic GEMM + bias + relu + BN epilogue --------------
__global__ __launch_bounds__(256) void gemm_bn_kernel(
    const float* __restrict__ A, const float* __restrict__ W,
    const float* __restrict__ bias, const float* __restrict__ g,
    const float* __restrict__ be, float* __restrict__ C, int Kin, int Cout) {
    __shared__ __align__(16) float shA[64][33];
    __shared__ __align__(16) float shB[32][68];
    const int t = threadIdx.x;
    const int r0 = blockIdx.x * 64;
    const int c0 = blockIdx.y * 64;
    const int tr = t >> 4, tc = t & 15;
    const float invs = 1.0f / sqrtf(1.0f + EPSF);
    float acc[16];
#pragma unroll
    for (int i = 0; i < 16; ++i) acc[i] = 0.0f;
    for (int k0 = 0; k0 < Kin; k0 += 32) {
#pragma unroll
        for (int e = t; e < 2048; e += 256) {
            int r = e >> 5, kk = e & 31;
            shA[r][kk] = A[(size_t)(r0 + r) * Kin + k0 + kk];
        }
#pragma unroll
        for (int e = t; e < 2048; e += 256) {
            int kk = e >> 6, cc = e & 63;
            shB[kk][cc] = W[(size_t)(k0 + kk) * Cout + c0 + cc];
        }
        __syncthreads();
        for (int kk = 0; kk < 32; ++kk) {
            float av[4];
#pragma unroll
            for (int i = 0; i < 4; ++i) av[i] = shA[4 * tr + i][kk];
            const float4 wv = *(const float4*)&shB[kk][4 * tc];
            const float wa[4] = {wv.x, wv.y, wv.z, wv.w};
#pragma unroll
            for (int i = 0; i < 4; ++i)
#pragma unroll
                for (int jj = 0; jj < 4; ++jj)
                    acc[i * 4 + jj] = fmaf(av[i], wa[jj], acc[i * 4 + jj]);
        }
        __syncthreads();
    }
#pragma unroll
    for (int i = 0; i < 4; ++i)
#pragma unroll
        for (int jj = 0; jj < 4; ++jj) {
            int col = c0 + 4 * tc + jj;
            float z = fmaxf(acc[i * 4 + jj] + bias[col], 0.0f);
            C[(size_t)(r0 + 4 * tr + i) * Cout + col] = g[col] * z * invs + be[col];
        }
}

// ---------------- K8: final 128 -> 2 layer ----------------------------------
__global__ __launch_bounds__(256) void lo2_kernel(
    const float* __restrict__ in, const float* __restrict__ w,
    const float* __restrict__ b, const float* __restrict__ g,
    const float* __restrict__ be, float* __restrict__ out) {
    __shared__ float sw[256];
    const int t = threadIdx.x;
    sw[t] = w[t];
    __syncthreads();
    const int row = blockIdx.x * 256 + t;
    const float invs = 1.0f / sqrtf(1.0f + EPSF);
    float a0 = b[0], a1 = b[1];
    const float* R = in + (size_t)row * 128;
    for (int k = 0; k < 128; ++k) {
        float a = R[k];
        a0 = fmaf(a, sw[k * 2], a0);
        a1 = fmaf(a, sw[k * 2 + 1], a1);
    }
    a0 = fmaxf(a0, 0.0f);
    a1 = fmaxf(a1, 0.0f);
    out[(size_t)row * 2]     = g[0] * a0 * invs + be[0];
    out[(size_t)row * 2 + 1] = g[1] * a1 * invs + be[1];
}

// ---------------------------------------------------------------------------
extern "C" void kernel_launch(void* const* d_in, const int* in_sizes, int n_in,
                              void* d_out, int out_size, void* d_ws, size_t ws_size,
                              hipStream_t stream) {
    const float* x      = (const float*)d_in[0];
    const float* pos    = (const float*)d_in[1];
    const float* lin_w  = (const float*)d_in[3];
    const float* lin_b  = (const float*)d_in[4];
    const float* sa_w1  = (const float*)d_in[5];
    const float* sa_b1  = (const float*)d_in[6];
    const float* sa_g1  = (const float*)d_in[7];
    const float* sa_be1 = (const float*)d_in[8];
    const float* sa_w2  = (const float*)d_in[9];
    const float* sa_b2  = (const float*)d_in[10];
    const float* sa_g2  = (const float*)d_in[11];
    const float* sa_be2 = (const float*)d_in[12];
    const float* fp_w1  = (const float*)d_in[13];
    const float* fp_b1  = (const float*)d_in[14];
    const float* fp_g1  = (const float*)d_in[15];
    const float* fp_be1 = (const float*)d_in[16];
    const float* fp_w2  = (const float*)d_in[17];
    const float* fp_b2  = (const float*)d_in[18];
    const float* fp_g2  = (const float*)d_in[19];
    const float* fp_be2 = (const float*)d_in[20];
    const float* lo_w1  = (const float*)d_in[21];
    const float* lo_b1  = (const float*)d_in[22];
    const float* lo_g1  = (const float*)d_in[23];
    const float* lo_be1 = (const float*)d_in[24];
    const float* lo_w2  = (const float*)d_in[25];
    const float* lo_b2  = (const float*)d_in[26];
    const float* lo_g2  = (const float*)d_in[27];
    const float* lo_be2 = (const float*)d_in[28];

    float* ws = (float*)d_ws;
    size_t off = 0;
    auto alloc = [&](size_t n) { float* p = ws + off; off += n; return p; };
    float* xb    = alloc(4 * 4096 * 128);
    float* q1    = alloc(4 * 2048 * 3);
    float* q2    = alloc(4 * 1024 * 3);
    float* q3    = alloc(4 * 512 * 3);
    float* h1    = alloc(4 * 2048 * 128);
    float* h2    = alloc(4 * 1024 * 128);
    float* h3    = alloc(4 * 512 * 128);
    int2* pairs1 = (int2*)alloc(4 * 2048 * 64 * 2);
    int2* pairs2 = (int2*)alloc(4 * 1024 * 64 * 2);
    int2* pairs3 = (int2*)alloc(4 * 512 * 64 * 2);
    unsigned* ctrs = (unsigned*)alloc(64);   // [0],[16],[32] per level
    int* kidx    = (int*)alloc(4 * 4096 * 3);
    float* kw    = alloc(4 * 4096 * 3);
    float* cat   = alloc(4 * 4096 * 256);
    float* mbuf  = alloc(4 * 4096 * 256);
    float* xfA   = alloc(4 * 4096 * 128);
    float* xfB   = alloc(4 * 4096 * 128);
    if (ws_size < off * sizeof(float)) return;

    lin_in_kernel<<<16384, 128, 0, stream>>>(x, lin_w, lin_b, xb);

    // ---- SA level 0: 4096 -> 2048 ----
    fps_kernel<4096, 512><<<4, 512, 0, stream>>>(pos, q1, 2048);
    zero_kernel<<<(4 * 2048 * 128 + 255) / 256, 256, 0, stream>>>(h1, 4 * 2048 * 128, ctrs + 0);
    nbr_kernel<64, 2><<<4096, 128, 0, stream>>>(pos, q1, pairs1, ctrs + 0, 4096, 2048);
    sa_fused_kernel<<<8192, 256, 0, stream>>>(xb, pos, q1, pairs1, ctrs + 0,
        sa_w1, sa_b1, sa_g1, sa_be1, sa_w2, sa_b2, sa_g2, sa_be2, h1, 11, 12);

    // ---- SA level 1: 2048 -> 1024 ----
    fps_kernel<2048, 256><<<4, 256, 0, stream>>>(q1, q2, 1024);
    zero_kernel<<<(4 * 1024 * 128 + 255) / 256, 256, 0, stream>>>(h2, 4 * 1024 * 128, ctrs + 16);
    nbr_kernel<32, 4><<<1024, 256, 0, stream>>>(q1, q2, pairs2, ctrs + 16, 2048, 1024);
    sa_fused_kernel<<<4096, 256, 0, stream>>>(h1, q1, q2, pairs2, ctrs + 16,
        sa_w1 + 131 * 131, sa_b1 + 131, sa_g1 + 131, sa_be1 + 131,
        sa_w2 + 131 * 128, sa_b2 + 128, sa_g2 + 128, sa_be2 + 128, h2, 10, 11);

    // ---- SA level 2: 1024 -> 512 ----
    fps_kernel<1024, 256><<<4, 256, 0, stream>>>(q2, q3, 512);
    zero_kernel<<<(4 * 512 * 128 + 255) / 256, 256, 0, stream>>>(h3, 4 * 512 * 128, ctrs + 32);
    nbr_kernel<16, 4><<<512, 256, 0, stream>>>(q2, q3, pairs3, ctrs + 32, 1024, 512);
    sa_fused_kernel<<<2048, 256, 0, stream>>>(h2, q2, q3, pairs3, ctrs + 32,
        sa_w1 + 2 * 131 * 131, sa_b1 + 2 * 131, sa_g1 + 2 * 131, sa_be1 + 2 * 131,
        sa_w2 + 2 * 131 * 128, sa_b2 + 2 * 128, sa_g2 + 2 * 128, sa_be2 + 2 * 128, h3, 9, 10);

    // ---- FP step 0 (mi=2): 512 -> 1024 ----
    knn_kernel<<<(4 * 1024) / 256, 256, 0, stream>>>(q2, q3, kidx, kw, 1024, 512);
    interp_cat_kernel<<<4 * 1024, 256, 0, stream>>>(h3, h2, kidx, kw, cat, 1024, 512);
    gemm_bn_kernel<<<dim3(4096 / 64, 4), 256, 0, stream>>>(cat,
        fp_w1 + 2 * 256 * 256, fp_b1 + 2 * 256, fp_g1 + 2 * 256, fp_be1 + 2 * 256,
        mbuf, 256, 256);
    gemm_bn_kernel<<<dim3(4096 / 64, 2), 256, 0, stream>>>(mbuf,
        fp_w2 + 2 * 256 * 128, fp_b2 + 2 * 128, fp_g2 + 2 * 128, fp_be2 + 2 * 128,
        xfA, 256, 128);

    // ---- FP step 1 (mi=1): 1024 -> 2048 ----
    knn_kernel<<<(4 * 2048) / 256, 256, 0, stream>>>(q1, q2, kidx, kw, 2048, 1024);
    interp_cat_kernel<<<4 * 2048, 256, 0, stream>>>(xfA, h1, kidx, kw, cat, 2048, 1024);
    gemm_bn_kernel<<<dim3(8192 / 64, 4), 256, 0, stream>>>(cat,
        fp_w1 + 256 * 256, fp_b1 + 256, fp_g1 + 256, fp_be1 + 256,
        mbuf, 256, 256);
    gemm_bn_kernel<<<dim3(8192 / 64, 2), 256, 0, stream>>>(mbuf,
        fp_w2 + 256 * 128, fp_b2 + 128, fp_g2 + 128, fp_be2 + 128,
        xfB, 256, 128);

    // ---- FP step 2 (mi=0): 2048 -> 4096 ----
    knn_kernel<<<(4 * 4096) / 256, 256, 0, stream>>>(pos, q1, kidx, kw, 4096, 2048);
    interp_cat_kernel<<<4 * 4096, 256, 0, stream>>>(xfB, xb, kidx, kw, cat, 4096, 2048);
    gemm_bn_kernel<<<dim3(16384 / 64, 4), 256, 0, stream>>>(cat,
        fp_w1, fp_b1, fp_g1, fp_be1, mbuf, 256, 256);
    gemm_bn_kernel<<<dim3(16384 / 64, 2), 256, 0, stream>>>(mbuf,
        fp_w2, fp_b2, fp_g2, fp_be2, xfA, 256, 128);

    // ---- output MLP ----
    gemm_bn_kernel<<<dim3(16384 / 64, 2), 256, 0, stream>>>(xfA,
        lo_w1, lo_b1, lo_g1, lo_be1, mbuf, 128, 128);
    lo2_kernel<<<16384 / 256, 256, 0, stream>>>(mbuf, lo_w2, lo_b2, lo_g2, lo_be2,
        (float*)d_out);
}

// Round 5
// 3994.922 us; speedup vs baseline: 1.5943x; 1.1825x over previous
//
#include <hip/hip_runtime.h>
#include <cstddef>

// ---------------------------------------------------------------------------
// PointNet++ (B=4, N0=4096, NIN=16, NH=128, NOUT=2, DEPTH=3, K=64, R=2, KNN=3)
// fp32. Selection paths (FPS argmax, radius top-K, 3-NN) use non-contracted
// fp32 ops + first-index tie-breaks to match the reference bit-for-bit.
// FPS: blocked point->thread assignment so lane/slot order == index order;
// value-only f32 DPP max trees + bit-equal ballot for index recovery; winner
// coords via broadcast LDS read; q indices buffered in LDS. One barrier/step.
// SA MLP = compacted batched GEMM over valid (center,point) pairs with
// atomicMax (uint bits, values >= 0) scatter for the max-aggregation.
// ---------------------------------------------------------------------------

#define EPSF 1e-5f

__device__ __forceinline__ float d2_rn(float dx, float dy, float dz) {
    return __fadd_rn(__fadd_rn(__fmul_rn(dx, dx), __fmul_rn(dy, dy)), __fmul_rn(dz, dz));
}

template <int CTRL, int RMASK>
__device__ __forceinline__ float dpp_max_f32(float v) {
    int o = __builtin_amdgcn_update_dpp(__float_as_int(v), __float_as_int(v),
                                        CTRL, RMASK, 0xf, false);
    return fmaxf(v, __int_as_float(o));
}

// ---------------- K1: lin_in  xb = relu(x @ W + b), rows=16384 --------------
__global__ __launch_bounds__(128) void lin_in_kernel(
    const float* __restrict__ x, const float* __restrict__ w,
    const float* __restrict__ b, float* __restrict__ xb) {
    __shared__ float sx[16];
    int row = blockIdx.x;
    int t = threadIdx.x;
    if (t < 16) sx[t] = x[row * 16 + t];
    __syncthreads();
    float acc = b[t];
#pragma unroll
    for (int k = 0; k < 16; ++k) acc = fmaf(sx[k], w[k * 128 + t], acc);
    xb[row * 128 + t] = fmaxf(acc, 0.0f);
}

// ---------------- K2: FPS, short fixed chain --------------------------------
template <int N, int NT>
__global__ __launch_bounds__(NT) void fps_kernel(
    const float* __restrict__ pts, float* __restrict__ q, int m) {
    constexpr int PPT = N / NT;
    constexpr int NW = NT / 64;
    __shared__ float s_px[N], s_py[N], s_pz[N];
    __shared__ int   s_qi[N / 2];
    __shared__ __align__(8) float2 s_slot[2][NW];   // (value, index-bits)
    const int b = blockIdx.x, t = threadIdx.x;
    const int wave = t >> 6, lane = t & 63;
    const int base = t * PPT;                        // blocked assignment
    const float* P = pts + (size_t)b * N * 3;
    float rx[PPT], ry[PPT], rz[PPT], dmin[PPT];
#pragma unroll
    for (int j = 0; j < PPT; ++j) {
        int i = base + j;
        float x = P[i * 3], y = P[i * 3 + 1], z = P[i * 3 + 2];
        rx[j] = x; ry[j] = y; rz[j] = z; dmin[j] = 1e30f;
        s_px[i] = x; s_py[i] = y; s_pz[i] = z;
    }
    float lx = P[0], ly = P[1], lz = P[2];
    if (t == 0) s_qi[0] = 0;

    for (int step = 1; step < m; ++step) {
        // ---- dmin update + per-thread argmax (first j on ties via strict >) ----
        float bv = -1.0f; int bj = 0;
#pragma unroll
        for (int j = 0; j < PPT; ++j) {
            float d = d2_rn(rx[j] - lx, ry[j] - ly, rz[j] - lz);
            float dm = fminf(dmin[j], d);
            dmin[j] = dm;
            if (dm > bv) { bv = dm; bj = j; }
        }
        const int bidx = base + bj;

        // ---- in-wave value-only f32 DPP max tree -> lane 63 ----
        float v = bv;
        v = dpp_max_f32<0x111, 0xf>(v);   // row_shr:1
        v = dpp_max_f32<0x112, 0xf>(v);   // row_shr:2
        v = dpp_max_f32<0x114, 0xf>(v);   // row_shr:4
        v = dpp_max_f32<0x118, 0xf>(v);   // row_shr:8
        v = dpp_max_f32<0x142, 0xa>(v);   // row_bcast:15
        v = dpp_max_f32<0x143, 0xc>(v);   // row_bcast:31
        const float mv = __int_as_float(__builtin_amdgcn_readlane(__float_as_int(v), 63));
        // lowest matching lane == lowest index (blocked assignment, bit-exact max)
        unsigned long long mb = __ballot(bv == mv);
        const int wl = __ffsll((long long)mb) - 1;
        const int wbi = __builtin_amdgcn_readlane(bidx, wl);

        const int p = step & 1;
        if (lane == 0) s_slot[p][wave] = make_float2(mv, __int_as_float(wbi));
        __syncthreads();

        // ---- cross-wave: lane-parallel slot read + small tree + ballot ----
        float2 sl = s_slot[p][lane & (NW - 1)];
        float gvt = sl.x;
        gvt = dpp_max_f32<0x111, 0xf>(gvt);
        gvt = dpp_max_f32<0x112, 0xf>(gvt);
        if (NW == 8) gvt = dpp_max_f32<0x114, 0xf>(gvt);
        const float gm = __int_as_float(
            __builtin_amdgcn_readlane(__float_as_int(gvt), NW - 1));
        unsigned long long gb = __ballot((lane < NW) && (sl.x == gm));
        const int gl = __ffsll((long long)gb) - 1;        // lowest slot == lowest index
        const int gi = __builtin_amdgcn_readlane(__float_as_int(sl.y), gl);

        // ---- winner coords: broadcast LDS reads (conflict-free) ----
        lx = s_px[gi]; ly = s_py[gi]; lz = s_pz[gi];
        if (t == 0) s_qi[step] = gi;
    }
    __syncthreads();
    for (int e = t; e < m; e += NT) {
        int gi = s_qi[e];
        size_t o = ((size_t)b * m + e) * 3;
        q[o] = s_px[gi]; q[o + 1] = s_py[gi]; q[o + 2] = s_pz[gi];
    }
}

// ---------------- K3: zero hout + pair counter ------------------------------
__global__ void zero_kernel(float* __restrict__ buf, int n, unsigned* __restrict__ counter) {
    int i = blockIdx.x * 256 + threadIdx.x;
    if (i < n) buf[i] = 0.0f;
    if (i == 0) *counter = 0u;
}

// ---------------- K4: radius-ball K=64 selection -> compacted pair list -----
template <int CHUNK, int WAVES>
__global__ void nbr_kernel(const float* __restrict__ pts, const float* __restrict__ q,
                           int2* __restrict__ pairs, unsigned* __restrict__ counter,
                           int n, int m) {
    __shared__ float dst[WAVES * CHUNK * 64];
    const int w = threadIdx.x >> 6, lane = threadIdx.x & 63;
    const int c = blockIdx.x * WAVES + w;
    const int b = c / m;
    float* D = dst + w * CHUNK * 64;
    const float* P = pts + (size_t)b * n * 3;
    const float qx = q[(size_t)c * 3 + 0];
    const float qy = q[(size_t)c * 3 + 1];
    const float qz = q[(size_t)c * 3 + 2];
    for (int s = 0; s < CHUNK; ++s) {
        int i = s * 64 + lane;
        float d2 = d2_rn(P[i * 3] - qx, P[i * 3 + 1] - qy, P[i * 3 + 2] - qz);
        D[i] = (d2 <= 4.0f) ? d2 : 1e30f;   // RADIUS^2 = 4
    }
    int my_g = -1;
    int cnt = 0;
    for (int round = 0; round < 64; ++round) {
        float bv = 3e38f;
        int bi = 0x7fffffff;
        for (int s = 0; s < CHUNK; ++s) {
            int i = s * 64 + lane;
            float v = D[i];
            if (v < bv) { bv = v; bi = i; }   // strict <: lowest-index tie-break
        }
#pragma unroll
        for (int off = 32; off >= 1; off >>= 1) {
            float ov = __shfl_xor(bv, off, 64);
            int   oi = __shfl_xor(bi, off, 64);
            if (ov < bv || (ov == bv && oi < bi)) { bv = ov; bi = oi; }
        }
        if (bv > 1e29f) break;               // only invalid/removed remain (uniform)
        if (round == lane) my_g = bi;
        if (lane == (bi & 63)) D[bi] = 3e38f;
        ++cnt;
    }
    unsigned base = 0;
    if (lane == 0) base = atomicAdd(counter, (unsigned)cnt);
    base = (unsigned)__shfl((int)base, 0, 64);
    if (lane < cnt) pairs[base + lane] = make_int2(c, my_g);
}

// ---------------- K5: fused SA MLP over compacted rows ----------------------
__global__ __launch_bounds__(256) void sa_fused_kernel(
    const float* __restrict__ xx, const float* __restrict__ pts,
    const float* __restrict__ q, const int2* __restrict__ pairs,
    const unsigned* __restrict__ vcount,
    const float* __restrict__ w1, const float* __restrict__ b1,
    const float* __restrict__ g1, const float* __restrict__ be1,
    const float* __restrict__ w2, const float* __restrict__ b2,
    const float* __restrict__ g2, const float* __restrict__ be2,
    float* __restrict__ hout, int lm, int ln) {
    __shared__ __align__(16) float shA[64][132];   // gather -> H1 -> out (reused)
    __shared__ __align__(16) float shW[32][132];
    __shared__ int sh_c[64], sh_g[64];
    const int t = threadIdx.x;
    const int V = (int)*vcount;
    const int r0 = blockIdx.x * 64;
    if (r0 >= V) return;
    if (t < 64) {
        int r = r0 + t;
        if (r < V) { int2 p = pairs[r]; sh_c[t] = p.x; sh_g[t] = p.y; }
        else { sh_c[t] = -1; sh_g[t] = 0; }
    }
    __syncthreads();

    // ---- gather A: 64 rows x 132 cols (33 float4 chunks per row) ----
    for (int e = t; e < 64 * 33; e += 256) {
        int row = e / 33, cid = e - row * 33;
        int c = sh_c[row];
        float4 v = make_float4(0.f, 0.f, 0.f, 0.f);
        if (c >= 0) {
            int g = sh_g[row];
            int b = c >> lm;
            size_t pt = ((size_t)(b << ln) + g);
            if (cid < 32) {
                v = *(const float4*)(xx + (pt << 7) + cid * 4);
            } else {
                const float* P = pts + pt * 3;
                const float* Q = q + (size_t)c * 3;
                v.x = P[0] - Q[0]; v.y = P[1] - Q[1]; v.z = P[2] - Q[2]; v.w = 0.f;
            }
        }
        *(float4*)&shA[row][cid * 4] = v;
    }
    __syncthreads();

    const float invs = 1.0f / sqrtf(1.0f + EPSF);
    const int tr = t >> 4, tc = t & 15;       // rows 4tr..4tr+3, cols 8tc..8tc+7
    const int xrow = t >> 2, xcol = t & 3;    // extra cols 128..131
    float acc[32];
#pragma unroll
    for (int i = 0; i < 32; ++i) acc[i] = 0.0f;
    float accx = 0.0f;

    // ---- layer 1: K=132 (rows/cols >=131 zero-padded) ----
    for (int k0 = 0; k0 < 132; k0 += 32) {
        const int kc = (132 - k0 < 32) ? (132 - k0) : 32;
        for (int e = t; e < kc * 132; e += 256) {
            int kk = e / 132, j = e - kk * 132;
            int k = k0 + kk;
            shW[kk][j] = (k < 131 && j < 131) ? w1[k * 131 + j] : 0.0f;
        }
        __syncthreads();
        for (int kk = 0; kk < kc; ++kk) {
            const int k = k0 + kk;
            float a0 = shA[4 * tr + 0][k], a1 = shA[4 * tr + 1][k];
            float a2 = shA[4 * tr + 2][k], a3 = shA[4 * tr + 3][k];
            const float4 w0 = *(const float4*)&shW[kk][8 * tc];
            const float4 w1v = *(const float4*)&shW[kk][8 * tc + 4];
            const float wa[8] = {w0.x, w0.y, w0.z, w0.w, w1v.x, w1v.y, w1v.z, w1v.w};
#pragma unroll
            for (int j = 0; j < 8; ++j) {
                acc[0 * 8 + j] = fmaf(a0, wa[j], acc[0 * 8 + j]);
                acc[1 * 8 + j] = fmaf(a1, wa[j], acc[1 * 8 + j]);
                acc[2 * 8 + j] = fmaf(a2, wa[j], acc[2 * 8 + j]);
                acc[3 * 8 + j] = fmaf(a3, wa[j], acc[3 * 8 + j]);
            }
            accx = fmaf(shA[xrow][k], shW[kk][128 + xcol], accx);
        }
        __syncthreads();
    }
    // epilogue 1 -> H1 into shA
#pragma unroll
    for (int i = 0; i < 4; ++i)
#pragma unroll
        for (int j = 0; j < 8; ++j) {
            int col = 8 * tc + j;
            float z = fmaxf(acc[i * 8 + j] + b1[col], 0.0f);
            shA[4 * tr + i][col] = g1[col] * z * invs + be1[col];
        }
    if (xcol < 3) {
        int col = 128 + xcol;
        float z = fmaxf(accx + b1[col], 0.0f);
        shA[xrow][col] = g1[col] * z * invs + be1[col];
    } else {
        shA[xrow][131] = 0.0f;   // zero K-pad col (w2 row 131 is also zeroed)
    }

    // ---- layer 2: 132 -> 128 ----
#pragma unroll
    for (int i = 0; i < 32; ++i) acc[i] = 0.0f;
    for (int k0 = 0; k0 < 132; k0 += 32) {
        const int kc = (132 - k0 < 32) ? (132 - k0) : 32;
        for (int e = t; e < kc * 132; e += 256) {
            int kk = e / 132, j = e - kk * 132;
            int k = k0 + kk;
            shW[kk][j] = (k < 131 && j < 128) ? w2[k * 128 + j] : 0.0f;
        }
        __syncthreads();
        for (int kk = 0; kk < kc; ++kk) {
            const int k = k0 + kk;
            float a0 = shA[4 * tr + 0][k], a1 = shA[4 * tr + 1][k];
            float a2 = shA[4 * tr + 2][k], a3 = shA[4 * tr + 3][k];
            const float4 w0 = *(const float4*)&shW[kk][8 * tc];
            const float4 w1v = *(const float4*)&shW[kk][8 * tc + 4];
            const float wa[8] = {w0.x, w0.y, w0.z, w0.w, w1v.x, w1v.y, w1v.z, w1v.w};
#pragma unroll
            for (int j = 0; j < 8; ++j) {
                acc[0 * 8 + j] = fmaf(a0, wa[j], acc[0 * 8 + j]);
                acc[1 * 8 + j] = fmaf(a1, wa[j], acc[1 * 8 + j]);
                acc[2 * 8 + j] = fmaf(a2, wa[j], acc[2 * 8 + j]);
                acc[3 * 8 + j] = fmaf(a3, wa[j], acc[3 * 8 + j]);
            }
        }
        __syncthreads();
    }
    // epilogue 2 -> out into shA (cols 0..127)
#pragma unroll
    for (int i = 0; i < 4; ++i)
#pragma unroll
        for (int j = 0; j < 8; ++j) {
            int col = 8 * tc + j;
            float z = fmaxf(acc[i * 8 + j] + b2[col], 0.0f);
            shA[4 * tr + i][col] = g2[col] * z * invs + be2[col];
        }
    __syncthreads();

    // ---- segmented max over contiguous same-center rows + atomic scatter ----
    if (t < 128) {
        const int col = t;
        float run = -1.0f;
        int cur = sh_c[0];
        for (int row = 0; row < 64; ++row) {
            int c = sh_c[row];
            if (c != cur) {
                if (cur >= 0)
                    atomicMax((unsigned*)&hout[((size_t)cur << 7) + col], __float_as_uint(run));
                run = -1.0f; cur = c;
            }
            run = fmaxf(run, shA[row][col]);
        }
        if (cur >= 0)
            atomicMax((unsigned*)&hout[((size_t)cur << 7) + col], __float_as_uint(run));
    }
}

// ---------------- K6a: 3-NN search + inverse-d2 weights --------------------
__global__ __launch_bounds__(256) void knn_kernel(
    const float* __restrict__ pf, const float* __restrict__ pc,
    int* __restrict__ kidx, float* __restrict__ kw, int nf, int nc) {
    const int tg = blockIdx.x * 256 + threadIdx.x;
    const int b = tg / nf;
    const float* F = pf + (size_t)tg * 3;
    const float fx = F[0], fy = F[1], fz = F[2];
    const float* C = pc + (size_t)b * nc * 3;
    float b0 = 1e30f, b1 = 1e30f, b2 = 1e30f;
    int i0 = 0, i1 = 0, i2 = 0;
    for (int j = 0; j < nc; ++j) {
        float d2 = d2_rn(C[j * 3] - fx, C[j * 3 + 1] - fy, C[j * 3 + 2] - fz);
        if (d2 < b0)      { b2 = b1; i2 = i1; b1 = b0; i1 = i0; b0 = d2; i0 = j; }
        else if (d2 < b1) { b2 = b1; i2 = i1; b1 = d2; i1 = j; }
        else if (d2 < b2) { b2 = d2; i2 = j; }
    }
    float w0 = 1.0f / fmaxf(b0, 1e-16f);
    float w1 = 1.0f / fmaxf(b1, 1e-16f);
    float w2 = 1.0f / fmaxf(b2, 1e-16f);
    float inv = 1.0f / (w0 + w1 + w2);
    size_t o = (size_t)tg * 3;
    kidx[o] = i0; kidx[o + 1] = i1; kidx[o + 2] = i2;
    kw[o] = w0 * inv; kw[o + 1] = w1 * inv; kw[o + 2] = w2 * inv;
}

// ---------------- K6b: interpolate + concat skip -> cat[f][256] -------------
__global__ __launch_bounds__(256) void interp_cat_kernel(
    const float* __restrict__ xc, const float* __restrict__ xs,
    const int* __restrict__ kidx, const float* __restrict__ kw,
    float* __restrict__ cat, int nf, int nc) {
    const int f = blockIdx.x;
    const int t = threadIdx.x;
    const int b = f / nf;
    const size_t o = (size_t)f * 3;
    if (t < 128) {
        int i0 = kidx[o], i1 = kidx[o + 1], i2 = kidx[o + 2];
        float w0 = kw[o], w1 = kw[o + 1], w2 = kw[o + 2];
        const float* X = xc + (size_t)b * nc * 128;
        float y = w0 * X[(size_t)i0 * 128 + t] + w1 * X[(size_t)i1 * 128 + t] +
                  w2 * X[(size_t)i2 * 128 + t];
        cat[(size_t)f * 256 + t] = y;
    } else {
        cat[(size_t)f * 256 + t] = xs[(size_t)f * 128 + (t - 128)];
    }
}

// ---------------- K7: generic GEMM + bias + relu + BN epilogue --------------
__global__ __launch_bounds__(256) void gemm_bn_kernel(
    const float* __restrict__ A, const float* __restrict__ W,
    const float* __restrict__ bias, const float* __restrict__ g,
    const float* __restrict__ be, float* __restrict__ C, int Kin, int Cout) {
    __shared__ __align__(16) float shA[64][33];
    __shared__ __align__(16) float shB[32][68];
    const int t = threadIdx.x;
    const int r0 = blockIdx.x * 64;
    const int c0 = blockIdx.y * 64;
    const int tr = t >> 4, tc = t & 15;
    const float invs = 1.0f / sqrtf(1.0f + EPSF);
    float acc[16];
#pragma unroll
    for (int i = 0; i < 16; ++i) acc[i] = 0.0f;
    for (int k0 = 0; k0 < Kin; k0 += 32) {
#pragma unroll
        for (int e = t; e < 2048; e += 256) {
            int r = e >> 5, kk = e & 31;
            shA[r][kk] = A[(size_t)(r0 + r) * Kin + k0 + kk];
        }
#pragma unroll
        for (int e = t; e < 2048; e += 256) {
            int kk = e >> 6, cc = e & 63;
            shB[kk][cc] = W[(size_t)(k0 + kk) * Cout + c0 + cc];
        }
        __syncthreads();
        for (int kk = 0; kk < 32; ++kk) {
            float av[4];
#pragma unroll
            for (int i = 0; i < 4; ++i) av[i] = shA[4 * tr + i][kk];
            const float4 wv = *(const float4*)&shB[kk][4 * tc];
            const float wa[4] = {wv.x, wv.y, wv.z, wv.w};
#pragma unroll
            for (int i = 0; i < 4; ++i)
#pragma unroll
                for (int jj = 0; jj < 4; ++jj)
                    acc[i * 4 + jj] = fmaf(av[i], wa[jj], acc[i * 4 + jj]);
        }
        __syncthreads();
    }
#pragma unroll
    for (int i = 0; i < 4; ++i)
#pragma unroll
        for (int jj = 0; jj < 4; ++jj) {
            int col = c0 + 4 * tc + jj;
            float z = fmaxf(acc[i * 4 + jj] + bias[col], 0.0f);
            C[(size_t)(r0 + 4 * tr + i) * Cout + col] = g[col] * z * invs + be[col];
        }
}

// ---------------- K8: final 128 -> 2 layer ----------------------------------
__global__ __launch_bounds__(256) void lo2_kernel(
    const float* __restrict__ in, const float* __restrict__ w,
    const float* __restrict__ b, const float* __restrict__ g,
    const float* __restrict__ be, float* __restrict__ out) {
    __shared__ float sw[256];
    const int t = threadIdx.x;
    sw[t] = w[t];
    __syncthreads();
    const int row = blockIdx.x * 256 + t;
    const float invs = 1.0f / sqrtf(1.0f + EPSF);
    float a0 = b[0], a1 = b[1];
    const float* R = in + (size_t)row * 128;
    for (int k = 0; k < 128; ++k) {
        float a = R[k];
        a0 = fmaf(a, sw[k * 2], a0);
        a1 = fmaf(a, sw[k * 2 + 1], a1);
    }
    a0 = fmaxf(a0, 0.0f);
    a1 = fmaxf(a1, 0.0f);
    out[(size_t)row * 2]     = g[0] * a0 * invs + be[0];
    out[(size_t)row * 2 + 1] = g[1] * a1 * invs + be[1];
}

// ---------------------------------------------------------------------------
extern "C" void kernel_launch(void* const* d_in, const int* in_sizes, int n_in,
                              void* d_out, int out_size, void* d_ws, size_t ws_size,
                              hipStream_t stream) {
    const float* x      = (const float*)d_in[0];
    const float* pos    = (const float*)d_in[1];
    const float* lin_w  = (const float*)d_in[3];
    const float* lin_b  = (const float*)d_in[4];
    const float* sa_w1  = (const float*)d_in[5];
    const float* sa_b1  = (const float*)d_in[6];
    const float* sa_g1  = (const float*)d_in[7];
    const float* sa_be1 = (const float*)d_in[8];
    const float* sa_w2  = (const float*)d_in[9];
    const float* sa_b2  = (const float*)d_in[10];
    const float* sa_g2  = (const float*)d_in[11];
    const float* sa_be2 = (const float*)d_in[12];
    const float* fp_w1  = (const float*)d_in[13];
    const float* fp_b1  = (const float*)d_in[14];
    const float* fp_g1  = (const float*)d_in[15];
    const float* fp_be1 = (const float*)d_in[16];
    const float* fp_w2  = (const float*)d_in[17];
    const float* fp_b2  = (const float*)d_in[18];
    const float* fp_g2  = (const float*)d_in[19];
    const float* fp_be2 = (const float*)d_in[20];
    const float* lo_w1  = (const float*)d_in[21];
    const float* lo_b1  = (const float*)d_in[22];
    const float* lo_g1  = (const float*)d_in[23];
    const float* lo_be1 = (const float*)d_in[24];
    const float* lo_w2  = (const float*)d_in[25];
    const float* lo_b2  = (const float*)d_in[26];
    const float* lo_g2  = (const float*)d_in[27];
    const float* lo_be2 = (const float*)d_in[28];

    float* ws = (float*)d_ws;
    size_t off = 0;
    auto alloc = [&](size_t n) { float* p = ws + off; off += n; return p; };
    float* xb    = alloc(4 * 4096 * 128);
    float* q1    = alloc(4 * 2048 * 3);
    float* q2    = alloc(4 * 1024 * 3);
    float* q3    = alloc(4 * 512 * 3);
    float* h1    = alloc(4 * 2048 * 128);
    float* h2    = alloc(4 * 1024 * 128);
    float* h3    = alloc(4 * 512 * 128);
    int2* pairs1 = (int2*)alloc(4 * 2048 * 64 * 2);
    int2* pairs2 = (int2*)alloc(4 * 1024 * 64 * 2);
    int2* pairs3 = (int2*)alloc(4 * 512 * 64 * 2);
    unsigned* ctrs = (unsigned*)alloc(64);   // [0],[16],[32] per level
    int* kidx    = (int*)alloc(4 * 4096 * 3);
    float* kw    = alloc(4 * 4096 * 3);
    float* cat   = alloc(4 * 4096 * 256);
    float* mbuf  = alloc(4 * 4096 * 256);
    float* xfA   = alloc(4 * 4096 * 128);
    float* xfB   = alloc(4 * 4096 * 128);
    if (ws_size < off * sizeof(float)) return;

    lin_in_kernel<<<16384, 128, 0, stream>>>(x, lin_w, lin_b, xb);

    // ---- SA level 0: 4096 -> 2048 ----
    fps_kernel<4096, 256><<<4, 256, 0, stream>>>(pos, q1, 2048);
    zero_kernel<<<(4 * 2048 * 128 + 255) / 256, 256, 0, stream>>>(h1, 4 * 2048 * 128, ctrs + 0);
    nbr_kernel<64, 2><<<4096, 128, 0, stream>>>(pos, q1, pairs1, ctrs + 0, 4096, 2048);
    sa_fused_kernel<<<8192, 256, 0, stream>>>(xb, pos, q1, pairs1, ctrs + 0,
        sa_w1, sa_b1, sa_g1, sa_be1, sa_w2, sa_b2, sa_g2, sa_be2, h1, 11, 12);

    // ---- SA level 1: 2048 -> 1024 ----
    fps_kernel<2048, 256><<<4, 256, 0, stream>>>(q1, q2, 1024);
    zero_kernel<<<(4 * 1024 * 128 + 255) / 256, 256, 0, stream>>>(h2, 4 * 1024 * 128, ctrs + 16);
    nbr_kernel<32, 4><<<1024, 256, 0, stream>>>(q1, q2, pairs2, ctrs + 16, 2048, 1024);
    sa_fused_kernel<<<4096, 256, 0, stream>>>(h1, q1, q2, pairs2, ctrs + 16,
        sa_w1 + 131 * 131, sa_b1 + 131, sa_g1 + 131, sa_be1 + 131,
        sa_w2 + 131 * 128, sa_b2 + 128, sa_g2 + 128, sa_be2 + 128, h2, 10, 11);

    // ---- SA level 2: 1024 -> 512 ----
    fps_kernel<1024, 256><<<4, 256, 0, stream>>>(q2, q3, 512);
    zero_kernel<<<(4 * 512 * 128 + 255) / 256, 256, 0, stream>>>(h3, 4 * 512 * 128, ctrs + 32);
    nbr_kernel<16, 4><<<512, 256, 0, stream>>>(q2, q3, pairs3, ctrs + 32, 1024, 512);
    sa_fused_kernel<<<2048, 256, 0, stream>>>(h2, q2, q3, pairs3, ctrs + 32,
        sa_w1 + 2 * 131 * 131, sa_b1 + 2 * 131, sa_g1 + 2 * 131, sa_be1 + 2 * 131,
        sa_w2 + 2 * 131 * 128, sa_b2 + 2 * 128, sa_g2 + 2 * 128, sa_be2 + 2 * 128, h3, 9, 10);

    // ---- FP step 0 (mi=2): 512 -> 1024 ----
    knn_kernel<<<(4 * 1024) / 256, 256, 0, stream>>>(q2, q3, kidx, kw, 1024, 512);
    interp_cat_kernel<<<4 * 1024, 256, 0, stream>>>(h3, h2, kidx, kw, cat, 1024, 512);
    gemm_bn_kernel<<<dim3(4096 / 64, 4), 256, 0, stream>>>(cat,
        fp_w1 + 2 * 256 * 256, fp_b1 + 2 * 256, fp_g1 + 2 * 256, fp_be1 + 2 * 256,
        mbuf, 256, 256);
    gemm_bn_kernel<<<dim3(4096 / 64, 2), 256, 0, stream>>>(mbuf,
        fp_w2 + 2 * 256 * 128, fp_b2 + 2 * 128, fp_g2 + 2 * 128, fp_be2 + 2 * 128,
        xfA, 256, 128);

    // ---- FP step 1 (mi=1): 1024 -> 2048 ----
    knn_kernel<<<(4 * 2048) / 256, 256, 0, stream>>>(q1, q2, kidx, kw, 2048, 1024);
    interp_cat_kernel<<<4 * 2048, 256, 0, stream>>>(xfA, h1, kidx, kw, cat, 2048, 1024);
    gemm_bn_kernel<<<dim3(8192 / 64, 4), 256, 0, stream>>>(cat,
        fp_w1 + 256 * 256, fp_b1 + 256, fp_g1 + 256, fp_be1 + 256,
        mbuf, 256, 256);
    gemm_bn_kernel<<<dim3(8192 / 64, 2), 256, 0, stream>>>(mbuf,
        fp_w2 + 256 * 128, fp_b2 + 128, fp_g2 + 128, fp_be2 + 128,
        xfB, 256, 128);

    // ---- FP step 2 (mi=0): 2048 -> 4096 ----
    knn_kernel<<<(4 * 4096) / 256, 256, 0, stream>>>(pos, q1, kidx, kw, 4096, 2048);
    interp_cat_kernel<<<4 * 4096, 256, 0, stream>>>(xfB, xb, kidx, kw, cat, 4096, 2048);
    gemm_bn_kernel<<<dim3(16384 / 64, 4), 256, 0, stream>>>(cat,
        fp_w1, fp_b1, fp_g1, fp_be1, mbuf, 256, 256);
    gemm_bn_kernel<<<dim3(16384 / 64, 2), 256, 0, stream>>>(mbuf,
        fp_w2, fp_b2, fp_g2, fp_be2, xfA, 256, 128);

    // ---- output MLP ----
    gemm_bn_kernel<<<dim3(16384 / 64, 2), 256, 0, stream>>>(xfA,
        lo_w1, lo_b1, lo_g1, lo_be1, mbuf, 128, 128);
    lo2_kernel<<<16384 / 256, 256, 0, stream>>>(mbuf, lo_w2, lo_b2, lo_g2, lo_be2,
        (float*)d_out);
}

// Round 7
// 3973.506 us; speedup vs baseline: 1.6029x; 1.0054x over previous
//
#include <hip/hip_runtime.h>
#include <cstddef>

// ---------------------------------------------------------------------------
// PointNet++ (B=4, N0=4096, NIN=16, NH=128, NOUT=2, DEPTH=3, K=64, R=2, KNN=3)
// fp32. Selection paths (FPS argmax, radius top-K, 3-NN) use non-contracted
// fp32 ops + first-index tie-breaks to match the reference bit-for-bit.
// FPS (round-5 proven structure): blocked point->thread assignment so
// lane/slot order == index order; value-only f32 DPP max trees + bit-equal
// ballot for index recovery; winner coords via broadcast LDS read; q indices
// buffered in LDS. One barrier/step.
// SA MLP = compacted batched GEMM over valid (center,point) pairs with
// atomicMax (uint bits, values >= 0) scatter for the max-aggregation.
// ---------------------------------------------------------------------------

#define EPSF 1e-5f

__device__ __forceinline__ float d2_rn(float dx, float dy, float dz) {
    return __fadd_rn(__fadd_rn(__fmul_rn(dx, dx), __fmul_rn(dy, dy)), __fmul_rn(dz, dz));
}

template <int CTRL, int RMASK>
__device__ __forceinline__ float dpp_max_f32(float v) {
    int o = __builtin_amdgcn_update_dpp(__float_as_int(v), __float_as_int(v),
                                        CTRL, RMASK, 0xf, false);
    return fmaxf(v, __int_as_float(o));
}

// ---------------- K1: lin_in  xb = relu(x @ W + b), rows=16384 --------------
__global__ __launch_bounds__(128) void lin_in_kernel(
    const float* __restrict__ x, const float* __restrict__ w,
    const float* __restrict__ b, float* __restrict__ xb) {
    __shared__ float sx[16];
    int row = blockIdx.x;
    int t = threadIdx.x;
    if (t < 16) sx[t] = x[row * 16 + t];
    __syncthreads();
    float acc = b[t];
#pragma unroll
    for (int k = 0; k < 16; ++k) acc = fmaf(sx[k], w[k * 128 + t], acc);
    xb[row * 128 + t] = fmaxf(acc, 0.0f);
}

// ---------------- K2: FPS, round-5 proven structure -------------------------
template <int N, int NT>
__global__ __launch_bounds__(NT) void fps_kernel(
    const float* __restrict__ pts, float* __restrict__ q, int m) {
    constexpr int PPT = N / NT;
    constexpr int NW = NT / 64;
    __shared__ float s_px[N], s_py[N], s_pz[N];
    __shared__ int   s_qi[N / 2];
    __shared__ __align__(8) float2 s_slot[2][NW];   // (value, index-bits)
    const int b = blockIdx.x, t = threadIdx.x;
    const int wave = t >> 6, lane = t & 63;
    const int base = t * PPT;                        // blocked assignment
    const float* P = pts + (size_t)b * N * 3;
    float rx[PPT], ry[PPT], rz[PPT], dmin[PPT];
#pragma unroll
    for (int j = 0; j < PPT; ++j) {
        int i = base + j;
        float x = P[i * 3], y = P[i * 3 + 1], z = P[i * 3 + 2];
        rx[j] = x; ry[j] = y; rz[j] = z; dmin[j] = 1e30f;
        s_px[i] = x; s_py[i] = y; s_pz[i] = z;
    }
    float lx = P[0], ly = P[1], lz = P[2];
    if (t == 0) s_qi[0] = 0;

    for (int step = 1; step < m; ++step) {
        // ---- dmin update + per-thread argmax (first j on ties via strict >) ----
        float bv = -1.0f; int bj = 0;
#pragma unroll
        for (int j = 0; j < PPT; ++j) {
            float d = d2_rn(rx[j] - lx, ry[j] - ly, rz[j] - lz);
            float dm = fminf(dmin[j], d);
            dmin[j] = dm;
            if (dm > bv) { bv = dm; bj = j; }
        }
        const int bidx = base + bj;

        // ---- in-wave value-only f32 DPP max tree -> lane 63 ----
        float v = bv;
        v = dpp_max_f32<0x111, 0xf>(v);   // row_shr:1
        v = dpp_max_f32<0x112, 0xf>(v);   // row_shr:2
        v = dpp_max_f32<0x114, 0xf>(v);   // row_shr:4
        v = dpp_max_f32<0x118, 0xf>(v);   // row_shr:8
        v = dpp_max_f32<0x142, 0xa>(v);   // row_bcast:15
        v = dpp_max_f32<0x143, 0xc>(v);   // row_bcast:31
        const float mv = __int_as_float(__builtin_amdgcn_readlane(__float_as_int(v), 63));
        // lowest matching lane == lowest index (blocked assignment, bit-exact max)
        unsigned long long mb = __ballot(bv == mv);
        const int wl = __ffsll((long long)mb) - 1;
        const int wbi = __builtin_amdgcn_readlane(bidx, wl);

        const int p = step & 1;
        if (lane == 0) s_slot[p][wave] = make_float2(mv, __int_as_float(wbi));
        __syncthreads();

        // ---- cross-wave: lane-parallel slot read + small tree + ballot ----
        float2 sl = s_slot[p][lane & (NW - 1)];
        float gvt = sl.x;
        gvt = dpp_max_f32<0x111, 0xf>(gvt);
        gvt = dpp_max_f32<0x112, 0xf>(gvt);
        if (NW == 8) gvt = dpp_max_f32<0x114, 0xf>(gvt);
        const float gm = __int_as_float(
            __builtin_amdgcn_readlane(__float_as_int(gvt), NW - 1));
        unsigned long long gb = __ballot((lane < NW) && (sl.x == gm));
        const int gl = __ffsll((long long)gb) - 1;        // lowest slot == lowest index
        const int gi = __builtin_amdgcn_readlane(__float_as_int(sl.y), gl);

        // ---- winner coords: broadcast LDS reads (conflict-free) ----
        lx = s_px[gi]; ly = s_py[gi]; lz = s_pz[gi];
        if (t == 0) s_qi[step] = gi;
    }
    __syncthreads();
    for (int e = t; e < m; e += NT) {
        int gi = s_qi[e];
        size_t o = ((size_t)b * m + e) * 3;
        q[o] = s_px[gi]; q[o + 1] = s_py[gi]; q[o + 2] = s_pz[gi];
    }
}

// ---------------- K3: zero h1|h2|h3 (contiguous) + all pair counters --------
__global__ void zero_all_kernel(float* __restrict__ buf, int n,
                                unsigned* __restrict__ ctrs) {
    int i = blockIdx.x * 256 + threadIdx.x;
    if (i < n) buf[i] = 0.0f;
    if (i < 3) ctrs[i * 16] = 0u;
}

// ---------------- K4: radius-ball K=64 selection -> compacted pair list -----
template <int CHUNK, int WAVES>
__global__ void nbr_kernel(const float* __restrict__ pts, const float* __restrict__ q,
                           int2* __restrict__ pairs, unsigned* __restrict__ counter,
                           int n, int m) {
    __shared__ float dst[WAVES * CHUNK * 64];
    const int w = threadIdx.x >> 6, lane = threadIdx.x & 63;
    const int c = blockIdx.x * WAVES + w;
    const int b = c / m;
    float* D = dst + w * CHUNK * 64;
    const float* P = pts + (size_t)b * n * 3;
    const float qx = q[(size_t)c * 3 + 0];
    const float qy = q[(size_t)c * 3 + 1];
    const float qz = q[(size_t)c * 3 + 2];
    for (int s = 0; s < CHUNK; ++s) {
        int i = s * 64 + lane;
        float d2 = d2_rn(P[i * 3] - qx, P[i * 3 + 1] - qy, P[i * 3 + 2] - qz);
        D[i] = (d2 <= 4.0f) ? d2 : 1e30f;   // RADIUS^2 = 4
    }
    int my_g = -1;
    int cnt = 0;
    for (int round = 0; round < 64; ++round) {
        float bv = 3e38f;
        int bi = 0x7fffffff;
        for (int s = 0; s < CHUNK; ++s) {
            int i = s * 64 + lane;
            float v = D[i];
            if (v < bv) { bv = v; bi = i; }   // strict <: lowest-index tie-break
        }
#pragma unroll
        for (int off = 32; off >= 1; off >>= 1) {
            float ov = __shfl_xor(bv, off, 64);
            int   oi = __shfl_xor(bi, off, 64);
            if (ov < bv || (ov == bv && oi < bi)) { bv = ov; bi = oi; }
        }
        if (bv > 1e29f) break;               // only invalid/removed remain (uniform)
        if (round == lane) my_g = bi;
        if (lane == (bi & 63)) D[bi] = 3e38f;
        ++cnt;
    }
    unsigned base = 0;
    if (lane == 0) base = atomicAdd(counter, (unsigned)cnt);
    base = (unsigned)__shfl((int)base, 0, 64);
    if (lane < cnt) pairs[base + lane] = make_int2(c, my_g);
}

// ---------------- K5: fused SA MLP over compacted rows ----------------------
__global__ __launch_bounds__(256) void sa_fused_kernel(
    const float* __restrict__ xx, const float* __restrict__ pts,
    const float* __restrict__ q, const int2* __restrict__ pairs,
    const unsigned* __restrict__ vcount,
    const float* __restrict__ w1, const float* __restrict__ b1,
    const float* __restrict__ g1, const float* __restrict__ be1,
    const float* __restrict__ w2, const float* __restrict__ b2,
    const float* __restrict__ g2, const float* __restrict__ be2,
    float* __restrict__ hout, int lm, int ln) {
    __shared__ __align__(16) float shA[64][132];   // gather -> H1 -> out (reused)
    __shared__ __align__(16) float shW[32][132];
    __shared__ int sh_c[64], sh_g[64];
    const int t = threadIdx.x;
    const int V = (int)*vcount;
    const int r0 = blockIdx.x * 64;
    if (r0 >= V) return;
    if (t < 64) {
        int r = r0 + t;
        if (r < V) { int2 p = pairs[r]; sh_c[t] = p.x; sh_g[t] = p.y; }
        else { sh_c[t] = -1; sh_g[t] = 0; }
    }
    __syncthreads();

    // ---- gather A: 64 rows x 132 cols (33 float4 chunks per row) ----
    for (int e = t; e < 64 * 33; e += 256) {
        int row = e / 33, cid = e - row * 33;
        int c = sh_c[row];
        float4 v = make_float4(0.f, 0.f, 0.f, 0.f);
        if (c >= 0) {
            int g = sh_g[row];
            int b = c >> lm;
            size_t pt = ((size_t)(b << ln) + g);
            if (cid < 32) {
                v = *(const float4*)(xx + (pt << 7) + cid * 4);
            } else {
                const float* P = pts + pt * 3;
                const float* Q = q + (size_t)c * 3;
                v.x = P[0] - Q[0]; v.y = P[1] - Q[1]; v.z = P[2] - Q[2]; v.w = 0.f;
            }
        }
        *(float4*)&shA[row][cid * 4] = v;
    }
    __syncthreads();

    const float invs = 1.0f / sqrtf(1.0f + EPSF);
    const int tr = t >> 4, tc = t & 15;       // rows 4tr..4tr+3, cols 8tc..8tc+7
    const int xrow = t >> 2, xcol = t & 3;    // extra cols 128..131
    float acc[32];
#pragma unroll
    for (int i = 0; i < 32; ++i) acc[i] = 0.0f;
    float accx = 0.0f;

    // ---- layer 1: K=132 (rows/cols >=131 zero-padded) ----
    for (int k0 = 0; k0 < 132; k0 += 32) {
        const int kc = (132 - k0 < 32) ? (132 - k0) : 32;
        for (int e = t; e < kc * 132; e += 256) {
            int kk = e / 132, j = e - kk * 132;
            int k = k0 + kk;
            shW[kk][j] = (k < 131 && j < 131) ? w1[k * 131 + j] : 0.0f;
        }
        __syncthreads();
        for (int kk = 0; kk < kc; ++kk) {
            const int k = k0 + kk;
            float a0 = shA[4 * tr + 0][k], a1 = shA[4 * tr + 1][k];
            float a2 = shA[4 * tr + 2][k], a3 = shA[4 * tr + 3][k];
            const float4 w0 = *(const float4*)&shW[kk][8 * tc];
            const float4 w1v = *(const float4*)&shW[kk][8 * tc + 4];
            const float wa[8] = {w0.x, w0.y, w0.z, w0.w, w1v.x, w1v.y, w1v.z, w1v.w};
#pragma unroll
            for (int j = 0; j < 8; ++j) {
                acc[0 * 8 + j] = fmaf(a0, wa[j], acc[0 * 8 + j]);
                acc[1 * 8 + j] = fmaf(a1, wa[j], acc[1 * 8 + j]);
                acc[2 * 8 + j] = fmaf(a2, wa[j], acc[2 * 8 + j]);
                acc[3 * 8 + j] = fmaf(a3, wa[j], acc[3 * 8 + j]);
            }
            accx = fmaf(shA[xrow][k], shW[kk][128 + xcol], accx);
        }
        __syncthreads();
    }
    // epilogue 1 -> H1 into shA
#pragma unroll
    for (int i = 0; i < 4; ++i)
#pragma unroll
        for (int j = 0; j < 8; ++j) {
            int col = 8 * tc + j;
            float z = fmaxf(acc[i * 8 + j] + b1[col], 0.0f);
            shA[4 * tr + i][col] = g1[col] * z * invs + be1[col];
        }
    if (xcol < 3) {
        int col = 128 + xcol;
        float z = fmaxf(accx + b1[col], 0.0f);
        shA[xrow][col] = g1[col] * z * invs + be1[col];
    } else {
        shA[xrow][131] = 0.0f;   // zero K-pad col (w2 row 131 is also zeroed)
    }

    // ---- layer 2: 132 -> 128 ----
#pragma unroll
    for (int i = 0; i < 32; ++i) acc[i] = 0.0f;
    for (int k0 = 0; k0 < 132; k0 += 32) {
        const int kc = (132 - k0 < 32) ? (132 - k0) : 32;
        for (int e = t; e < kc * 132; e += 256) {
            int kk = e / 132, j = e - kk * 132;
            int k = k0 + kk;
            shW[kk][j] = (k < 131 && j < 128) ? w2[k * 128 + j] : 0.0f;
        }
        __syncthreads();
        for (int kk = 0; kk < kc; ++kk) {
            const int k = k0 + kk;
            float a0 = shA[4 * tr + 0][k], a1 = shA[4 * tr + 1][k];
            float a2 = shA[4 * tr + 2][k], a3 = shA[4 * tr + 3][k];
            const float4 w0 = *(const float4*)&shW[kk][8 * tc];
            const float4 w1v = *(const float4*)&shW[kk][8 * tc + 4];
            const float wa[8] = {w0.x, w0.y, w0.z, w0.w, w1v.x, w1v.y, w1v.z, w1v.w};
#pragma unroll
            for (int j = 0; j < 8; ++j) {
                acc[0 * 8 + j] = fmaf(a0, wa[j], acc[0 * 8 + j]);
                acc[1 * 8 + j] = fmaf(a1, wa[j], acc[1 * 8 + j]);
                acc[2 * 8 + j] = fmaf(a2, wa[j], acc[2 * 8 + j]);
                acc[3 * 8 + j] = fmaf(a3, wa[j], acc[3 * 8 + j]);
            }
        }
        __syncthreads();
    }
    // epilogue 2 -> out into shA (cols 0..127)
#pragma unroll
    for (int i = 0; i < 4; ++i)
#pragma unroll
        for (int j = 0; j < 8; ++j) {
            int col = 8 * tc + j;
            float z = fmaxf(acc[i * 8 + j] + b2[col], 0.0f);
            shA[4 * tr + i][col] = g2[col] * z * invs + be2[col];
        }
    __syncthreads();

    // ---- segmented max over contiguous same-center rows + atomic scatter ----
    if (t < 128) {
        const int col = t;
        float run = -1.0f;
        int cur = sh_c[0];
        for (int row = 0; row < 64; ++row) {
            int c = sh_c[row];
            if (c != cur) {
                if (cur >= 0)
                    atomicMax((unsigned*)&hout[((size_t)cur << 7) + col], __float_as_uint(run));
                run = -1.0f; cur = c;
            }
            run = fmaxf(run, shA[row][col]);
        }
        if (cur >= 0)
            atomicMax((unsigned*)&hout[((size_t)cur << 7) + col], __float_as_uint(run));
    }
}

// ---------------- K6a: 3-NN search + inverse-d2 weights --------------------
__global__ __launch_bounds__(256) void knn_kernel(
    const float* __restrict__ pf, const float* __restrict__ pc,
    int* __restrict__ kidx, float* __restrict__ kw, int nf, int nc) {
    const int tg = blockIdx.x * 256 + threadIdx.x;
    const int b = tg / nf;
    const float* F = pf + (size_t)tg * 3;
    const float fx = F[0], fy = F[1], fz = F[2];
    const float* C = pc + (size_t)b * nc * 3;
    float b0 = 1e30f, b1 = 1e30f, b2 = 1e30f;
    int i0 = 0, i1 = 0, i2 = 0;
    for (int j = 0; j < nc; ++j) {
        float d2 = d2_rn(C[j * 3] - fx, C[j * 3 + 1] - fy, C[j * 3 + 2] - fz);
        if (d2 < b0)      { b2 = b1; i2 = i1; b1 = b0; i1 = i0; b0 = d2; i0 = j; }
        else if (d2 < b1) { b2 = b1; i2 = i1; b1 = d2; i1 = j; }
        else if (d2 < b2) { b2 = d2; i2 = j; }
    }
    float w0 = 1.0f / fmaxf(b0, 1e-16f);
    float w1 = 1.0f / fmaxf(b1, 1e-16f);
    float w2 = 1.0f / fmaxf(b2, 1e-16f);
    float inv = 1.0f / (w0 + w1 + w2);
    size_t o = (size_t)tg * 3;
    kidx[o] = i0; kidx[o + 1] = i1; kidx[o + 2] = i2;
    kw[o] = w0 * inv; kw[o + 1] = w1 * inv; kw[o + 2] = w2 * inv;
}

// ---------------- K6b: interpolate + concat skip -> cat[f][256] -------------
__global__ __launch_bounds__(256) void interp_cat_kernel(
    const float* __restrict__ xc, const float* __restrict__ xs,
    const int* __restrict__ kidx, const float* __restrict__ kw,
    float* __restrict__ cat, int nf, int nc) {
    const int f = blockIdx.x;
    const int t = threadIdx.x;
    const int b = f / nf;
    const size_t o = (size_t)f * 3;
    if (t < 128) {
        int i0 = kidx[o], i1 = kidx[o + 1], i2 = kidx[o + 2];
        float w0 = kw[o], w1 = kw[o + 1], w2 = kw[o + 2];
        const float* X = xc + (size_t)b * nc * 128;
        float y = w0 * X[(size_t)i0 * 128 + t] + w1 * X[(size_t)i1 * 128 + t] +
                  w2 * X[(size_t)i2 * 128 + t];
        cat[(size_t)f * 256 + t] = y;
    } else {
        cat[(size_t)f * 256 + t] = xs[(size_t)f * 128 + (t - 128)];
    }
}

// ---------------- K7: generic GEMM + bias + relu + BN epilogue --------------
__global__ __launch_bounds__(256) void gemm_bn_kernel(
    const float* __restrict__ A, const float* __restrict__ W,
    const float* __restrict__ bias, const float* __restrict__ g,
    const float* __restrict__ be, float* __restrict__ C, int Kin, int Cout) {
    __shared__ __align__(16) float shA[64][33];
    __shared__ __align__(16) float shB[32][68];
    const int t = threadIdx.x;
    const int r0 = blockIdx.x * 64;
    const int c0 = blockIdx.y * 64;
    const int tr = t >> 4, tc = t & 15;
    const float invs = 1.0f / sqrtf(1.0f + EPSF);
    float acc[16];
#pragma unroll
    for (int i = 0; i < 16; ++i) acc[i] = 0.0f;
    for (int k0 = 0; k0 < Kin; k0 += 32) {
#pragma unroll
        for (int e = t; e < 2048; e += 256) {
            int r = e >> 5, kk = e & 31;
            shA[r][kk] = A[(size_t)(r0 + r) * Kin + k0 + kk];
        }
#pragma unroll
        for (int e = t; e < 2048; e += 256) {
            int kk = e >> 6, cc = e & 63;
            shB[kk][cc] = W[(size_t)(k0 + kk) * Cout + c0 + cc];
        }
        __syncthreads();
        for (int kk = 0; kk < 32; ++kk) {
            float av[4];
#pragma unroll
            for (int i = 0; i < 4; ++i) av[i] = shA[4 * tr + i][kk];
            const float4 wv = *(const float4*)&shB[kk][4 * tc];
            const float wa[4] = {wv.x, wv.y, wv.z, wv.w};
#pragma unroll
            for (int i = 0; i < 4; ++i)
#pragma unroll
                for (int jj = 0; jj < 4; ++jj)
                    acc[i * 4 + jj] = fmaf(av[i], wa[jj], acc[i * 4 + jj]);
        }
        __syncthreads();
    }
#pragma unroll
    for (int i = 0; i < 4; ++i)
#pragma unroll
        for (int jj = 0; jj < 4; ++jj) {
            int col = c0 + 4 * tc + jj;
            float z = fmaxf(acc[i * 4 + jj] + bias[col], 0.0f);
            C[(size_t)(r0 + 4 * tr + i) * Cout + col] = g[col] * z * invs + be[col];
        }
}

// ---------------- K8: final 128 -> 2 layer ----------------------------------
__global__ __launch_bounds__(256) void lo2_kernel(
    const float* __restrict__ in, const float* __restrict__ w,
    const float* __restrict__ b, const float* __restrict__ g,
    const float* __restrict__ be, float* __restrict__ out) {
    __shared__ float sw[256];
    const int t = threadIdx.x;
    sw[t] = w[t];
    __syncthreads();
    const int row = blockIdx.x * 256 + t;
    const float invs = 1.0f / sqrtf(1.0f + EPSF);
    float a0 = b[0], a1 = b[1];
    const float* R = in + (size_t)row * 128;
    for (int k = 0; k < 128; ++k) {
        float a = R[k];
        a0 = fmaf(a, sw[k * 2], a0);
        a1 = fmaf(a, sw[k * 2 + 1], a1);
    }
    a0 = fmaxf(a0, 0.0f);
    a1 = fmaxf(a1, 0.0f);
    out[(size_t)row * 2]     = g[0] * a0 * invs + be[0];
    out[(size_t)row * 2 + 1] = g[1] * a1 * invs + be[1];
}

// ---------------------------------------------------------------------------
extern "C" void kernel_launch(void* const* d_in, const int* in_sizes, int n_in,
                              void* d_out, int out_size, void* d_ws, size_t ws_size,
                              hipStream_t stream) {
    const float* x      = (const float*)d_in[0];
    const float* pos    = (const float*)d_in[1];
    const float* lin_w  = (const float*)d_in[3];
    const float* lin_b  = (const float*)d_in[4];
    const float* sa_w1  = (const float*)d_in[5];
    const float* sa_b1  = (const float*)d_in[6];
    const float* sa_g1  = (const float*)d_in[7];
    const float* sa_be1 = (const float*)d_in[8];
    const float* sa_w2  = (const float*)d_in[9];
    const float* sa_b2  = (const float*)d_in[10];
    const float* sa_g2  = (const float*)d_in[11];
    const float* sa_be2 = (const float*)d_in[12];
    const float* fp_w1  = (const float*)d_in[13];
    const float* fp_b1  = (const float*)d_in[14];
    const float* fp_g1  = (const float*)d_in[15];
    const float* fp_be1 = (const float*)d_in[16];
    const float* fp_w2  = (const float*)d_in[17];
    const float* fp_b2  = (const float*)d_in[18];
    const float* fp_g2  = (const float*)d_in[19];
    const float* fp_be2 = (const float*)d_in[20];
    const float* lo_w1  = (const float*)d_in[21];
    const float* lo_b1  = (const float*)d_in[22];
    const float* lo_g1  = (const float*)d_in[23];
    const float* lo_be1 = (const float*)d_in[24];
    const float* lo_w2  = (const float*)d_in[25];
    const float* lo_b2  = (const float*)d_in[26];
    const float* lo_g2  = (const float*)d_in[27];
    const float* lo_be2 = (const float*)d_in[28];

    float* ws = (float*)d_ws;
    size_t off = 0;
    auto alloc = [&](size_t n) { float* p = ws + off; off += n; return p; };
    float* xb    = alloc(4 * 4096 * 128);
    float* q1    = alloc(4 * 2048 * 3);
    float* q2    = alloc(4 * 1024 * 3);
    float* q3    = alloc(4 * 512 * 3);
    float* h1    = alloc(4 * 2048 * 128);   // h1,h2,h3 contiguous for zero_all
    float* h2    = alloc(4 * 1024 * 128);
    float* h3    = alloc(4 * 512 * 128);
    int2* pairs1 = (int2*)alloc(4 * 2048 * 64 * 2);
    int2* pairs2 = (int2*)alloc(4 * 1024 * 64 * 2);
    int2* pairs3 = (int2*)alloc(4 * 512 * 64 * 2);
    unsigned* ctrs = (unsigned*)alloc(64);   // [0],[16],[32] per level
    int* kidx    = (int*)alloc(4 * 4096 * 3);
    float* kw    = alloc(4 * 4096 * 3);
    float* cat   = alloc(4 * 4096 * 256);
    float* mbuf  = alloc(4 * 4096 * 256);
    float* xfA   = alloc(4 * 4096 * 128);
    float* xfB   = alloc(4 * 4096 * 128);
    if (ws_size < off * sizeof(float)) return;

    // h1|h2|h3 span = 4*(2048+1024+512)*128 floats
    const int hz = 4 * 3584 * 128;
    zero_all_kernel<<<(hz + 255) / 256, 256, 0, stream>>>(h1, hz, ctrs);
    lin_in_kernel<<<16384, 128, 0, stream>>>(x, lin_w, lin_b, xb);

    // ---- SA level 0: 4096 -> 2048 ----
    fps_kernel<4096, 256><<<4, 256, 0, stream>>>(pos, q1, 2048);
    nbr_kernel<64, 2><<<4096, 128, 0, stream>>>(pos, q1, pairs1, ctrs + 0, 4096, 2048);
    sa_fused_kernel<<<8192, 256, 0, stream>>>(xb, pos, q1, pairs1, ctrs + 0,
        sa_w1, sa_b1, sa_g1, sa_be1, sa_w2, sa_b2, sa_g2, sa_be2, h1, 11, 12);

    // ---- SA level 1: 2048 -> 1024 ----
    fps_kernel<2048, 256><<<4, 256, 0, stream>>>(q1, q2, 1024);
    nbr_kernel<32, 4><<<1024, 256, 0, stream>>>(q1, q2, pairs2, ctrs + 16, 2048, 1024);
    sa_fused_kernel<<<4096, 256, 0, stream>>>(h1, q1, q2, pairs2, ctrs + 16,
        sa_w1 + 131 * 131, sa_b1 + 131, sa_g1 + 131, sa_be1 + 131,
        sa_w2 + 131 * 128, sa_b2 + 128, sa_g2 + 128, sa_be2 + 128, h2, 10, 11);

    // ---- SA level 2: 1024 -> 512 ----
    fps_kernel<1024, 256><<<4, 256, 0, stream>>>(q2, q3, 512);
    nbr_kernel<16, 4><<<512, 256, 0, stream>>>(q2, q3, pairs3, ctrs + 32, 1024, 512);
    sa_fused_kernel<<<2048, 256, 0, stream>>>(h2, q2, q3, pairs3, ctrs + 32,
        sa_w1 + 2 * 131 * 131, sa_b1 + 2 * 131, sa_g1 + 2 * 131, sa_be1 + 2 * 131,
        sa_w2 + 2 * 131 * 128, sa_b2 + 2 * 128, sa_g2 + 2 * 128, sa_be2 + 2 * 128, h3, 9, 10);

    // ---- FP step 0 (mi=2): 512 -> 1024 ----
    knn_kernel<<<(4 * 1024) / 256, 256, 0, stream>>>(q2, q3, kidx, kw, 1024, 512);
    interp_cat_kernel<<<4 * 1024, 256, 0, stream>>>(h3, h2, kidx, kw, cat, 1024, 512);
    gemm_bn_kernel<<<dim3(4096 / 64, 4), 256, 0, stream>>>(cat,
        fp_w1 + 2 * 256 * 256, fp_b1 + 2 * 256, fp_g1 + 2 * 256, fp_be1 + 2 * 256,
        mbuf, 256, 256);
    gemm_bn_kernel<<<dim3(4096 / 64, 2), 256, 0, stream>>>(mbuf,
        fp_w2 + 2 * 256 * 128, fp_b2 + 2 * 128, fp_g2 + 2 * 128, fp_be2 + 2 * 128,
        xfA, 256, 128);

    // ---- FP step 1 (mi=1): 1024 -> 2048 ----
    knn_kernel<<<(4 * 2048) / 256, 256, 0, stream>>>(q1, q2, kidx, kw, 2048, 1024);
    interp_cat_kernel<<<4 * 2048, 256, 0, stream>>>(xfA, h1, kidx, kw, cat, 2048, 1024);
    gemm_bn_kernel<<<dim3(8192 / 64, 4), 256, 0, stream>>>(cat,
        fp_w1 + 256 * 256, fp_b1 + 256, fp_g1 + 256, fp_be1 + 256,
        mbuf, 256, 256);
    gemm_bn_kernel<<<dim3(8192 / 64, 2), 256, 0, stream>>>(mbuf,
        fp_w2 + 256 * 128, fp_b2 + 128, fp_g2 + 128, fp_be2 + 128,
        xfB, 256, 128);

    // ---- FP step 2 (mi=0): 2048 -> 4096 ----
    knn_kernel<<<(4 * 4096) / 256, 256, 0, stream>>>(pos, q1, kidx, kw, 4096, 2048);
    interp_cat_kernel<<<4 * 4096, 256, 0, stream>>>(xfB, xb, kidx, kw, cat, 4096, 2048);
    gemm_bn_kernel<<<dim3(16384 / 64, 4), 256, 0, stream>>>(cat,
        fp_w1, fp_b1, fp_g1, fp_be1, mbuf, 256, 256);
    gemm_bn_kernel<<<dim3(16384 / 64, 2), 256, 0, stream>>>(mbuf,
        fp_w2, fp_b2, fp_g2, fp_be2, xfA, 256, 128);

    // ---- output MLP ----
    gemm_bn_kernel<<<dim3(16384 / 64, 2), 256, 0, stream>>>(xfA,
        lo_w1, lo_b1, lo_g1, lo_be1, mbuf, 128, 128);
    lo2_kernel<<<16384 / 256, 256, 0, stream>>>(mbuf, lo_w2, lo_b2, lo_g2, lo_be2,
        (float*)d_out);
}